// Round 1
// baseline (489.693 us; speedup 1.0000x reference)
//
#include <hip/hip_runtime.h>
#include <hip/hip_bf16.h>

// SpatialRelation on MI355X — round 5.
// R4: one fused k_steps kernel for all 3 GRU steps + attention.
// R5: fuse k_g0 (A@E0) INTO k_steps => k_main. The two kernels were 1:1
// block-for-block (16 rows each); fusion removes the grid-wide sync, the
// 8.4MB aOut/rowsum round-trip, and overlaps the HBM-bound A-read phase of
// late blocks with the MFMA/L2-bound step phase of early blocks.

typedef unsigned short u16;
typedef __attribute__((ext_vector_type(4))) float f32x4;
typedef __attribute__((ext_vector_type(8))) short bf16x8;

#define DI static __device__ __forceinline__

DI u16 f2bf(float f) {
    unsigned u = __builtin_bit_cast(unsigned, f);
    return (u16)((u + 0x7fffu + ((u >> 16) & 1u)) >> 16);  // RNE
}

DI bf16x8 cvt8(float4 a, float4 b) {
    u16 tmp[8] = {f2bf(a.x), f2bf(a.y), f2bf(a.z), f2bf(a.w),
                  f2bf(b.x), f2bf(b.y), f2bf(b.z), f2bf(b.w)};
    return *(const bf16x8*)tmp;
}

// B-operand image: element (k,n) at (((k>>5)*128+n)*4 + (((k>>3)&3)^((n>>1)&3)))*8 + (k&7)
DI int imgIdx(int k, int n) {
    return (((k >> 5) * 128 + n) * 4 + (((k >> 3) & 3) ^ ((n >> 1) & 3))) * 8 + (k & 7);
}
// B fragment (16B) direct from a weight/edge image in global memory.
DI bf16x8 wfragG(const u16* __restrict__ img, int kc, int tt, int l15, int quad) {
    return *(const bf16x8*)&img[(((kc * 128 + tt * 16 + l15) * 4) + (quad ^ ((l15 >> 1) & 3))) * 8];
}

#define MFMA16(a, b, c) __builtin_amdgcn_mfma_f32_16x16x32_bf16(a, b, c, 0, 0, 0)

// ---------------------------------------------------------------- prep 1
__global__ __launch_bounds__(256) void k_prep1(
    const float* __restrict__ linkW, const float* __restrict__ resetW,
    const float* __restrict__ updateW, const float* __restrict__ transW,
    const float* __restrict__ attW1, const float* __restrict__ outW,
    float* __restrict__ W2, u16* __restrict__ linkImg, u16* __restrict__ WrImg,
    u16* __restrict__ WzImg, u16* __restrict__ WhImg, u16* __restrict__ attW1Img,
    u16* __restrict__ outWImg)
{
    int blk = blockIdx.x, t = threadIdx.x;
    if (blk < 256) {
        int idx = blk * 256 + t;
        int out = idx >> 2, q = idx & 3;
        int r = out >> 7, c = out & 127;
        const float* ar = linkW + r * 128 + q * 32;
        float acc = 0.f;
#pragma unroll
        for (int k = 0; k < 32; k++) acc += ar[k] * linkW[(q * 32 + k) * 128 + c];
        acc += __shfl_xor(acc, 1);
        acc += __shfl_xor(acc, 2);
        if (q == 0) W2[out] = acc;
    } else {
        const float* src; u16* dst; int base;
        if (blk < 260)      { src = resetW;  dst = WrImg;    base = 256; }
        else if (blk < 264) { src = updateW; dst = WzImg;    base = 260; }
        else if (blk < 268) { src = transW;  dst = WhImg;    base = 264; }
        else if (blk < 270) { src = linkW;   dst = linkImg;  base = 268; }
        else if (blk < 272) { src = attW1;   dst = attW1Img; base = 270; }
        else                { src = outW;    dst = outWImg;  base = 272; }
        int off = (blk - base) * 8192;
        for (int i = 0; i < 32; i++) {
            int e = off + t + i * 256;
            int k = e >> 7, n = e & 127;
            dst[imgIdx(k, n)] = f2bf(src[e]);
        }
    }
}

// ---------------------------------------------------------------- prep 2
__global__ __launch_bounds__(256) void k_prep2(
    const float* __restrict__ linkW, const float* __restrict__ linkb,
    const float* __restrict__ W2, u16* __restrict__ W3Img, float* __restrict__ ebias)
{
    int blk = blockIdx.x, t = threadIdx.x;
    if (blk < 256) {
        int idx = blk * 256 + t;
        int out = idx >> 2, q = idx & 3;
        int r = out >> 7, c = out & 127;
        const float* ar = W2 + r * 128 + q * 32;
        float acc = 0.f;
#pragma unroll
        for (int k = 0; k < 32; k++) acc += ar[k] * linkW[(q * 32 + k) * 128 + c];
        acc += __shfl_xor(acc, 1);
        acc += __shfl_xor(acc, 2);
        if (q == 0) W3Img[imgIdx(r, c)] = f2bf(acc);
    } else if (t < 128) {
        float acc = linkb[t];
#pragma unroll 8
        for (int k = 0; k < 128; k++) acc += linkb[k] * (W2[k * 128 + t] + linkW[k * 128 + t]);
        ebias[t] = acc;
    }
}

// ---------------------------------------------------------------- E transpose (+edge resid)
__global__ __launch_bounds__(256) void k_te(
    const float* __restrict__ E0, u16* __restrict__ Eswz, float* __restrict__ resid)
{
    __shared__ alignas(16) u16 sT[4096];
    __shared__ float sCol[128];
    int t = threadIdx.x, kc = blockIdx.x, b = blockIdx.y;
    const float* Eb = E0 + (size_t)b * 262144 + (size_t)kc * 32 * 128;
    if (t < 128) sCol[t] = 0.f;
    float part[4] = {0.f, 0.f, 0.f, 0.f};
    int ncol = (t & 31) * 4;
    for (int i = 0; i < 4; i++) {
        int f4i = t + i * 256;
        int k5 = f4i >> 5;
        float4 v = *(const float4*)&Eb[k5 * 128 + ncol];
        int g = k5 >> 3, o = k5 & 7;
        float vv[4] = {v.x, v.y, v.z, v.w};
#pragma unroll
        for (int j = 0; j < 4; j++) {
            int n = ncol + j;
            sT[(n * 4 + (g ^ ((n >> 1) & 3))) * 8 + o] = f2bf(vv[j]);
            part[j] += vv[j];
        }
    }
    __syncthreads();
#pragma unroll
    for (int j = 0; j < 4; j++) atomicAdd(&sCol[ncol + j], part[j]);
    u16* dst = Eswz + (size_t)b * 262144 + (size_t)kc * 4096;
    ((uint4*)dst)[t] = ((const uint4*)sT)[t];
    ((uint4*)dst)[t + 256] = ((const uint4*)sT)[t + 256];
    __syncthreads();
    if (t < 128) atomicAdd(&resid[b * 128 + t], sCol[t]);
}

// ---------------------------------------------------------------- FUSED: G0 = A@E0, then
// all 3 GRU steps + attention. Block = 16 rows; g0 phase splits K across the
// 4 waves (LDS fp32 reduction), result goes straight to LDS bf16 (sA) — no
// global round-trip, no grid-wide sync between the HBM-bound and MFMA-bound
// phases (later blocks stream A while earlier blocks run their step loops).
__global__ __launch_bounds__(256, 3) void k_main(
    const float* __restrict__ A, const u16* __restrict__ Eswz,
    const float* __restrict__ p0,
    const u16* __restrict__ linkImg, const u16* __restrict__ WrImg,
    const u16* __restrict__ WzImg, const u16* __restrict__ WhImg,
    const u16* __restrict__ attW1Img, const u16* __restrict__ outWImg,
    const float* __restrict__ link_b, const float* __restrict__ reset_b,
    const float* __restrict__ update_b, const float* __restrict__ trans_b,
    const float* __restrict__ att_b1, const float* __restrict__ att_W2,
    const float* __restrict__ att_b2, const float* __restrict__ out_b,
    float* __restrict__ atten, float* __restrict__ outPool,
    float* __restrict__ resid)
{
    __shared__ float sAcc[4][16][128];                 // 32 KB (g0 reduction)
    __shared__ float sRs[4][16];
    __shared__ alignas(16) u16 sA[16 * 136], sRP[16 * 136], sP[16 * 136];
    __shared__ float sRed[16];

    int t = threadIdx.x, wid = t >> 6, lane = t & 63, l15 = lane & 15, quad = lane >> 4;
    int bx = blockIdx.x;
    int g = bx >> 8, rmod = bx & 255;
    int b = (rmod & 7) + 8 * g;                        // XCD-affine batch mapping
    int s = (rmod >> 3) & 31;
    size_t r0 = (size_t)b * 512 + (size_t)s * 16;

    // ================= phase G0: acc = A[16 rows] @ E0 (K split across waves)
    {
        const u16* Eb = Eswz + (size_t)b * 262144;
        const float* Ar = A + (r0 + l15) * 2048;
        int kbase = wid * 16;

        f32x4 acc[8];
#pragma unroll
        for (int i = 0; i < 8; i++) acc[i] = (f32x4){0.f, 0.f, 0.f, 0.f};
        float rsum = 0.f;

        float4 xc = *(const float4*)&Ar[kbase * 32 + quad * 8];
        float4 yc = *(const float4*)&Ar[kbase * 32 + quad * 8 + 4];
        bf16x8 bc[8];
#pragma unroll
        for (int tt = 0; tt < 8; tt++) bc[tt] = wfragG(Eb, kbase, tt, l15, quad);

        for (int kc = 0; kc < 16; kc++) {
            int kg = kbase + kc;
            float4 xn, yn; bf16x8 bn[8];
            if (kc < 15) {
                xn = *(const float4*)&Ar[(kg + 1) * 32 + quad * 8];
                yn = *(const float4*)&Ar[(kg + 1) * 32 + quad * 8 + 4];
#pragma unroll
                for (int tt = 0; tt < 8; tt++) bn[tt] = wfragG(Eb, kg + 1, tt, l15, quad);
            }
            rsum += xc.x + xc.y + xc.z + xc.w + yc.x + yc.y + yc.z + yc.w;
            bf16x8 af = cvt8(xc, yc);
#pragma unroll
            for (int tt = 0; tt < 8; tt++) acc[tt] = MFMA16(af, bc[tt], acc[tt]);
            if (kc < 15) {
                xc = xn; yc = yn;
#pragma unroll
                for (int tt = 0; tt < 8; tt++) bc[tt] = bn[tt];
            }
        }
        rsum += __shfl_xor(rsum, 16);
        rsum += __shfl_xor(rsum, 32);
        if (quad == 0) sRs[wid][l15] = rsum;
#pragma unroll
        for (int tt = 0; tt < 8; tt++)
#pragma unroll
            for (int r = 0; r < 4; r++)
                sAcc[wid][quad * 4 + r][tt * 16 + l15] = acc[tt][r];
    }
    __syncthreads();
    // cross-wave reduce -> bf16 G0 straight into sA (step-loop A-operand buffer)
    {
        int row = t >> 4, c8 = (t & 15) * 8;
#pragma unroll
        for (int j = 0; j < 8; j++) {
            float v = sAcc[0][row][c8 + j] + sAcc[1][row][c8 + j] +
                      sAcc[2][row][c8 + j] + sAcc[3][row][c8 + j];
            sA[row * 136 + c8 + j] = f2bf(v);
        }
    }
    if (t < 16) sRed[t] = sRs[0][t] + sRs[1][t] + sRs[2][t] + sRs[3][t];  // rowsum(A)
    __syncthreads();

    // ================= phase steps: 3 GRU steps + attention (row-local)
    int wave = wid;
    int bb = b;
    int ttA = wave * 2, ttB = wave * 2 + 1;
    int colA = ttA * 16 + l15, colB = ttB * 16 + l15;

    // full-K A-operand fragments of a (=G0, from LDS) and p0
    bf16x8 aF[4], pF[4];
#pragma unroll
    for (int kc = 0; kc < 4; kc++) {
        aF[kc] = *(const bf16x8*)&sA[l15 * 136 + kc * 32 + quad * 8];
        float4 x = *(const float4*)&p0[(r0 + l15) * 128 + kc * 32 + quad * 8];
        float4 y = *(const float4*)&p0[(r0 + l15) * 128 + kc * 32 + quad * 8 + 4];
        pF[kc] = cvt8(x, y);
    }
    // own-col fp32 p state (C layout: rows quad*4+r)
    f32x4 pS[2];
#pragma unroll
    for (int j = 0; j < 2; j++)
#pragma unroll
        for (int r = 0; r < 4; r++)
            pS[j][r] = p0[(r0 + quad * 4 + r) * 128 + (wave * 2 + j) * 16 + l15];
    // node part of the residual: sum over this block's 16 rows, own cols
    {
        float s0 = pS[0][0] + pS[0][1] + pS[0][2] + pS[0][3];
        float s1 = pS[1][0] + pS[1][1] + pS[1][2] + pS[1][3];
        s0 += __shfl_xor(s0, 16); s0 += __shfl_xor(s0, 32);
        s1 += __shfl_xor(s1, 16); s1 += __shfl_xor(s1, 32);
        if (quad == 0) {
            atomicAdd(&resid[bb * 128 + colA], s0);
            atomicAdd(&resid[bb * 128 + colB], s1);
        }
    }
    float sv[4];
#pragma unroll
    for (int r = 0; r < 4; r++) sv[r] = sRed[quad * 4 + r];
    float lbA = link_b[colA], lbB = link_b[colB];
    float rbA = reset_b[colA], rbB = reset_b[colB];
    float ubA = update_b[colA], ubB = update_b[colB];
    float tbA = trans_b[colA], tbB = trans_b[colB];

    __syncthreads();                 // sA/sRed reads done before step-loop rewrites
    if (t < 16) sRed[t] = 0.f;       // reused as attention accumulator later

    f32x4 zero4 = {0.f, 0.f, 0.f, 0.f};
    for (int step = 0; step < 3; step++) {
        // ---- phase 1: a_new (own cols) = a @ linkW + rowsum*link_b
        f32x4 cA = zero4, cB = zero4;
#pragma unroll
        for (int kc = 0; kc < 4; kc++) {
            cA = MFMA16(aF[kc], wfragG(linkImg, kc, ttA, l15, quad), cA);
            cB = MFMA16(aF[kc], wfragG(linkImg, kc, ttB, l15, quad), cB);
        }
#pragma unroll
        for (int r = 0; r < 4; r++) {
            sA[(quad * 4 + r) * 136 + colA] = f2bf(cA[r] + sv[r] * lbA);
            sA[(quad * 4 + r) * 136 + colB] = f2bf(cB[r] + sv[r] * lbB);
        }
        __syncthreads();
#pragma unroll
        for (int kc = 0; kc < 4; kc++)
            aF[kc] = *(const bf16x8*)&sA[l15 * 136 + kc * 32 + quad * 8];
        // ---- phase 2: r, z (own cols), K=256 over [a_new, p]
        f32x4 rA = zero4, rB = zero4, zA = zero4, zB = zero4;
#pragma unroll
        for (int kc = 0; kc < 8; kc++) {
            bf16x8 af = (kc < 4) ? aF[kc] : pF[kc - 4];
            rA = MFMA16(af, wfragG(WrImg, kc, ttA, l15, quad), rA);
            rB = MFMA16(af, wfragG(WrImg, kc, ttB, l15, quad), rB);
            zA = MFMA16(af, wfragG(WzImg, kc, ttA, l15, quad), zA);
            zB = MFMA16(af, wfragG(WzImg, kc, ttB, l15, quad), zB);
        }
#pragma unroll
        for (int r = 0; r < 4; r++) {
            float rvA = 1.f / (1.f + __expf(-(rA[r] + rbA)));
            float rvB = 1.f / (1.f + __expf(-(rB[r] + rbB)));
            zA[r] = 1.f / (1.f + __expf(-(zA[r] + ubA)));
            zB[r] = 1.f / (1.f + __expf(-(zB[r] + ubB)));
            sRP[(quad * 4 + r) * 136 + colA] = f2bf(rvA * pS[0][r]);
            sRP[(quad * 4 + r) * 136 + colB] = f2bf(rvB * pS[1][r]);
        }
        __syncthreads();
        bf16x8 rpF[4];
#pragma unroll
        for (int kc = 0; kc < 4; kc++)
            rpF[kc] = *(const bf16x8*)&sRP[l15 * 136 + kc * 32 + quad * 8];
        // ---- phase 3: h (own cols); GRU update (fp32 p state in regs)
        f32x4 hA = zero4, hB = zero4;
#pragma unroll
        for (int kc = 0; kc < 8; kc++) {
            bf16x8 af = (kc < 4) ? aF[kc] : rpF[kc - 4];
            hA = MFMA16(af, wfragG(WhImg, kc, ttA, l15, quad), hA);
            hB = MFMA16(af, wfragG(WhImg, kc, ttB, l15, quad), hB);
        }
#pragma unroll
        for (int r = 0; r < 4; r++) {
            float h1 = tanhf(hA[r] + tbA), h2 = tanhf(hB[r] + tbB);
            pS[0][r] = (1.f - zA[r]) * pS[0][r] + zA[r] * h1;
            pS[1][r] = (1.f - zB[r]) * pS[1][r] + zB[r] * h2;
            sP[(quad * 4 + r) * 136 + colA] = f2bf(pS[0][r]);
            sP[(quad * 4 + r) * 136 + colB] = f2bf(pS[1][r]);
        }
        __syncthreads();
#pragma unroll
        for (int kc = 0; kc < 4; kc++)
            pF[kc] = *(const bf16x8*)&sP[l15 * 136 + kc * 32 + quad * 8];
    }
    // ---- attention + out (own cols), A-operand = p3 fragments
    f32x4 atA = zero4, atB = zero4, oA = zero4, oB = zero4;
#pragma unroll
    for (int kc = 0; kc < 4; kc++) {
        atA = MFMA16(pF[kc], wfragG(attW1Img, kc, ttA, l15, quad), atA);
        atB = MFMA16(pF[kc], wfragG(attW1Img, kc, ttB, l15, quad), atB);
        oA  = MFMA16(pF[kc], wfragG(outWImg,  kc, ttA, l15, quad), oA);
        oB  = MFMA16(pF[kc], wfragG(outWImg,  kc, ttB, l15, quad), oB);
    }
    float b1A = att_b1[colA], b1B = att_b1[colB];
    float w2A = att_W2[colA], w2B = att_W2[colB];
    float obA = out_b[colA],  obB = out_b[colB];
    float pr[4];
#pragma unroll
    for (int r = 0; r < 4; r++) {
        pr[r] = tanhf(atA[r] + b1A) * w2A + tanhf(atB[r] + b1B) * w2B;
        outPool[(r0 + quad * 4 + r) * 128 + colA] = tanhf(oA[r] + obA);
        outPool[(r0 + quad * 4 + r) * 128 + colB] = tanhf(oB[r] + obB);
    }
#pragma unroll
    for (int r = 0; r < 4; r++) {
        float v = pr[r];
        v += __shfl_xor(v, 1); v += __shfl_xor(v, 2);
        v += __shfl_xor(v, 4); v += __shfl_xor(v, 8);
        if (l15 == 0) atomicAdd(&sRed[quad * 4 + r], v);
    }
    __syncthreads();
    if (t < 16) atten[r0 + t] = sRed[t] + att_b2[0];
}

// ---------------------------------------------------------------- edges out: E0@W3 + ebias
__global__ __launch_bounds__(64) void k_eout(
    const float* __restrict__ E0, const u16* __restrict__ W3Img,
    const float* __restrict__ ebias, float* __restrict__ Eout)
{
    int t = threadIdx.x, l15 = t & 15, quad = t >> 4;
    size_t r0 = (size_t)blockIdx.x * 16;
    bf16x8 eF[4];
#pragma unroll
    for (int kc = 0; kc < 4; kc++) {
        float4 x = *(const float4*)&E0[(r0 + l15) * 128 + kc * 32 + quad * 8];
        float4 y = *(const float4*)&E0[(r0 + l15) * 128 + kc * 32 + quad * 8 + 4];
        eF[kc] = cvt8(x, y);
    }
    f32x4 acc[8];
#pragma unroll
    for (int i = 0; i < 8; i++) acc[i] = (f32x4){0.f, 0.f, 0.f, 0.f};
    {
        bf16x8 wc[8], wn[8];
#pragma unroll
        for (int tt = 0; tt < 8; tt++) wc[tt] = wfragG(W3Img, 0, tt, l15, quad);
#pragma unroll
        for (int kc = 0; kc < 4; kc++) {
            if (kc < 3)
#pragma unroll
                for (int tt = 0; tt < 8; tt++) wn[tt] = wfragG(W3Img, kc + 1, tt, l15, quad);
#pragma unroll
            for (int tt = 0; tt < 8; tt++) acc[tt] = MFMA16(eF[kc], wc[tt], acc[tt]);
            if (kc < 3)
#pragma unroll
                for (int tt = 0; tt < 8; tt++) wc[tt] = wn[tt];
        }
    }
#pragma unroll
    for (int tt = 0; tt < 8; tt++) {
        int col = tt * 16 + l15; float eb = ebias[col];
#pragma unroll
        for (int r = 0; r < 4; r++)
            Eout[(r0 + quad * 4 + r) * 128 + col] = acc[tt][r] + eb;
    }
}

// ---------------------------------------------------------------- softmax-pool + residual
__global__ __launch_bounds__(512) void k_fin(
    const float* __restrict__ atten, const float* __restrict__ outPool,
    const float* __restrict__ resid,
    float* __restrict__ outRes, float* __restrict__ outMul)
{
    __shared__ float swv[512];
    __shared__ float sred[512];
    __shared__ float sacc[4][128];
    int t = threadIdx.x, b = blockIdx.x;
    float a = atten[b * 512 + t];
    sred[t] = a; __syncthreads();
    for (int s = 256; s > 0; s >>= 1) { if (t < s) sred[t] = fmaxf(sred[t], sred[t + s]); __syncthreads(); }
    float mx = sred[0]; __syncthreads();
    float e = __expf(a - mx);
    swv[t] = e; sred[t] = e; __syncthreads();
    for (int s = 256; s > 0; s >>= 1) { if (t < s) sred[t] += sred[t + s]; __syncthreads(); }
    float Z = sred[0]; __syncthreads();
    int col = t & 127, q = t >> 7;
    const float* op = outPool + ((size_t)b * 512 + q * 128) * 128 + col;
    float accM = 0.f;
#pragma unroll 8
    for (int n = 0; n < 128; n++) accM += swv[q * 128 + n] * op[(size_t)n * 128];
    sacc[q][col] = accM;
    __syncthreads();
    if (t < 128) {
        float mulv = (sacc[0][t] + sacc[1][t] + sacc[2][t] + sacc[3][t]) / Z;
        float rv = resid[b * 128 + t] * (1.f / 2560.f);
        outMul[b * 128 + t] = mulv;
        outRes[b * 128 + t] = fmaxf(0.f, tanhf(mulv) + rv);
    }
}

// ================================================================ launch
extern "C" void kernel_launch(void* const* d_in, const int* in_sizes, int n_in,
                              void* d_out, int out_size, void* d_ws, size_t ws_size,
                              hipStream_t stream)
{
    const float* prop0  = (const float*)d_in[0];
    const float* edge0  = (const float*)d_in[1];
    const float* Amat   = (const float*)d_in[2];
    const float* linkW  = (const float*)d_in[4];
    const float* linkb  = (const float*)d_in[5];
    const float* resetW = (const float*)d_in[6];
    const float* resetb = (const float*)d_in[7];
    const float* updateW= (const float*)d_in[8];
    const float* updateb= (const float*)d_in[9];
    const float* transW = (const float*)d_in[10];
    const float* transb = (const float*)d_in[11];
    const float* attW1  = (const float*)d_in[12];
    const float* attb1  = (const float*)d_in[13];
    const float* attW2  = (const float*)d_in[14];
    const float* attb2  = (const float*)d_in[15];
    const float* outW   = (const float*)d_in[16];
    const float* outb   = (const float*)d_in[17];

    char* w = (char*)d_ws;
    u16*   ws_a_bf    = (u16*)(w);                    // (unused after R5 fusion)
    float* ws_rowsum  = (float*)(w + 4194304);        // (unused after R5 fusion)
    float* ws_atten   = (float*)(w + 4259840);        //    65,536 B
    float* ws_resid   = (float*)(w + 4325376);        //    16,384 B
    float* ws_W2      = (float*)(w + 4341760);        //    65,536 B
    float* ws_ebias   = (float*)(w + 4407296);        //       512 B
    u16*   ws_linkImg = (u16*)(w + 4407808);          //    32,768 B
    u16*   ws_W3Img   = (u16*)(w + 4440576);          //    32,768 B
    u16*   ws_WrImg   = (u16*)(w + 4473344);          //    65,536 B
    u16*   ws_WzImg   = (u16*)(w + 4538880);          //    65,536 B
    u16*   ws_WhImg   = (u16*)(w + 4604416);          //    65,536 B
    u16*   ws_attW1Img= (u16*)(w + 4669952);          //    32,768 B
    u16*   ws_outWImg = (u16*)(w + 4702720);          //    32,768 B (~4.7 MB)
    (void)ws_a_bf; (void)ws_rowsum;

    float* out_res  = (float*)d_out;
    float* out_mul  = out_res + 4096;
    float* out_edge = out_res + 8192;
    // Scratch inside d_out edge region (dead until k_eout, which runs last):
    u16*   Eswz     = (u16*)out_edge;                 // 16.78 MB
    float* outPool  = out_edge + 4194304;             // next 8.39 MB

    hipMemsetAsync(ws_resid, 0, 32 * 128 * sizeof(float), stream);
    k_prep1<<<274, 256, 0, stream>>>(linkW, resetW, updateW, transW, attW1, outW,
                                     ws_W2, ws_linkImg, ws_WrImg, ws_WzImg, ws_WhImg,
                                     ws_attW1Img, ws_outWImg);
    k_prep2<<<257, 256, 0, stream>>>(linkW, linkb, ws_W2, ws_W3Img, ws_ebias);
    k_te<<<dim3(64, 32), 256, 0, stream>>>(edge0, Eswz, ws_resid);
    k_main<<<1024, 256, 0, stream>>>(Amat, Eswz, prop0,
                                     ws_linkImg, ws_WrImg, ws_WzImg, ws_WhImg,
                                     ws_attW1Img, ws_outWImg,
                                     linkb, resetb, updateb, transb,
                                     attb1, attW2, attb2, outb,
                                     ws_atten, outPool, ws_resid);
    k_fin<<<32, 512, 0, stream>>>(ws_atten, outPool, ws_resid, out_res, out_mul);
    k_eout<<<4096, 64, 0, stream>>>(edge0, ws_W3Img, ws_ebias, out_edge);
}

// Round 2
// 417.679 us; speedup vs baseline: 1.1724x; 1.1724x over previous
//
#include <hip/hip_runtime.h>
#include <hip/hip_bf16.h>

// SpatialRelation on MI355X — round 6.
// R5 fused k_g0 into k_steps (k_main) but kept __launch_bounds__(256,3):
// unified VGPR+AGPR cap = 168/wave, fused peak live set > 168 => massive
// scratch spills (WRITE_SIZE 201MB vs 9MB expected, k_main 243us).
// R6: __launch_bounds__(256,2) => cap 256/wave. No spills; 2 blocks/CU
// (LDS 46.5KB would allow 3, unified RF is the binding constraint).

typedef unsigned short u16;
typedef __attribute__((ext_vector_type(4))) float f32x4;
typedef __attribute__((ext_vector_type(8))) short bf16x8;

#define DI static __device__ __forceinline__

DI u16 f2bf(float f) {
    unsigned u = __builtin_bit_cast(unsigned, f);
    return (u16)((u + 0x7fffu + ((u >> 16) & 1u)) >> 16);  // RNE
}

DI bf16x8 cvt8(float4 a, float4 b) {
    u16 tmp[8] = {f2bf(a.x), f2bf(a.y), f2bf(a.z), f2bf(a.w),
                  f2bf(b.x), f2bf(b.y), f2bf(b.z), f2bf(b.w)};
    return *(const bf16x8*)tmp;
}

// B-operand image: element (k,n) at (((k>>5)*128+n)*4 + (((k>>3)&3)^((n>>1)&3)))*8 + (k&7)
DI int imgIdx(int k, int n) {
    return (((k >> 5) * 128 + n) * 4 + (((k >> 3) & 3) ^ ((n >> 1) & 3))) * 8 + (k & 7);
}
// B fragment (16B) direct from a weight/edge image in global memory.
DI bf16x8 wfragG(const u16* __restrict__ img, int kc, int tt, int l15, int quad) {
    return *(const bf16x8*)&img[(((kc * 128 + tt * 16 + l15) * 4) + (quad ^ ((l15 >> 1) & 3))) * 8];
}

#define MFMA16(a, b, c) __builtin_amdgcn_mfma_f32_16x16x32_bf16(a, b, c, 0, 0, 0)

// ---------------------------------------------------------------- prep 1
__global__ __launch_bounds__(256) void k_prep1(
    const float* __restrict__ linkW, const float* __restrict__ resetW,
    const float* __restrict__ updateW, const float* __restrict__ transW,
    const float* __restrict__ attW1, const float* __restrict__ outW,
    float* __restrict__ W2, u16* __restrict__ linkImg, u16* __restrict__ WrImg,
    u16* __restrict__ WzImg, u16* __restrict__ WhImg, u16* __restrict__ attW1Img,
    u16* __restrict__ outWImg)
{
    int blk = blockIdx.x, t = threadIdx.x;
    if (blk < 256) {
        int idx = blk * 256 + t;
        int out = idx >> 2, q = idx & 3;
        int r = out >> 7, c = out & 127;
        const float* ar = linkW + r * 128 + q * 32;
        float acc = 0.f;
#pragma unroll
        for (int k = 0; k < 32; k++) acc += ar[k] * linkW[(q * 32 + k) * 128 + c];
        acc += __shfl_xor(acc, 1);
        acc += __shfl_xor(acc, 2);
        if (q == 0) W2[out] = acc;
    } else {
        const float* src; u16* dst; int base;
        if (blk < 260)      { src = resetW;  dst = WrImg;    base = 256; }
        else if (blk < 264) { src = updateW; dst = WzImg;    base = 260; }
        else if (blk < 268) { src = transW;  dst = WhImg;    base = 264; }
        else if (blk < 270) { src = linkW;   dst = linkImg;  base = 268; }
        else if (blk < 272) { src = attW1;   dst = attW1Img; base = 270; }
        else                { src = outW;    dst = outWImg;  base = 272; }
        int off = (blk - base) * 8192;
        for (int i = 0; i < 32; i++) {
            int e = off + t + i * 256;
            int k = e >> 7, n = e & 127;
            dst[imgIdx(k, n)] = f2bf(src[e]);
        }
    }
}

// ---------------------------------------------------------------- prep 2
__global__ __launch_bounds__(256) void k_prep2(
    const float* __restrict__ linkW, const float* __restrict__ linkb,
    const float* __restrict__ W2, u16* __restrict__ W3Img, float* __restrict__ ebias)
{
    int blk = blockIdx.x, t = threadIdx.x;
    if (blk < 256) {
        int idx = blk * 256 + t;
        int out = idx >> 2, q = idx & 3;
        int r = out >> 7, c = out & 127;
        const float* ar = W2 + r * 128 + q * 32;
        float acc = 0.f;
#pragma unroll
        for (int k = 0; k < 32; k++) acc += ar[k] * linkW[(q * 32 + k) * 128 + c];
        acc += __shfl_xor(acc, 1);
        acc += __shfl_xor(acc, 2);
        if (q == 0) W3Img[imgIdx(r, c)] = f2bf(acc);
    } else if (t < 128) {
        float acc = linkb[t];
#pragma unroll 8
        for (int k = 0; k < 128; k++) acc += linkb[k] * (W2[k * 128 + t] + linkW[k * 128 + t]);
        ebias[t] = acc;
    }
}

// ---------------------------------------------------------------- E transpose (+edge resid)
__global__ __launch_bounds__(256) void k_te(
    const float* __restrict__ E0, u16* __restrict__ Eswz, float* __restrict__ resid)
{
    __shared__ alignas(16) u16 sT[4096];
    __shared__ float sCol[128];
    int t = threadIdx.x, kc = blockIdx.x, b = blockIdx.y;
    const float* Eb = E0 + (size_t)b * 262144 + (size_t)kc * 32 * 128;
    if (t < 128) sCol[t] = 0.f;
    float part[4] = {0.f, 0.f, 0.f, 0.f};
    int ncol = (t & 31) * 4;
    for (int i = 0; i < 4; i++) {
        int f4i = t + i * 256;
        int k5 = f4i >> 5;
        float4 v = *(const float4*)&Eb[k5 * 128 + ncol];
        int g = k5 >> 3, o = k5 & 7;
        float vv[4] = {v.x, v.y, v.z, v.w};
#pragma unroll
        for (int j = 0; j < 4; j++) {
            int n = ncol + j;
            sT[(n * 4 + (g ^ ((n >> 1) & 3))) * 8 + o] = f2bf(vv[j]);
            part[j] += vv[j];
        }
    }
    __syncthreads();
#pragma unroll
    for (int j = 0; j < 4; j++) atomicAdd(&sCol[ncol + j], part[j]);
    u16* dst = Eswz + (size_t)b * 262144 + (size_t)kc * 4096;
    ((uint4*)dst)[t] = ((const uint4*)sT)[t];
    ((uint4*)dst)[t + 256] = ((const uint4*)sT)[t + 256];
    __syncthreads();
    if (t < 128) atomicAdd(&resid[b * 128 + t], sCol[t]);
}

// ---------------------------------------------------------------- FUSED: G0 = A@E0, then
// all 3 GRU steps + attention. Block = 16 rows; g0 phase splits K across the
// 4 waves (LDS fp32 reduction), result goes straight to LDS bf16 (sA) — no
// global round-trip, no grid-wide sync between the HBM-bound and MFMA-bound
// phases (later blocks stream A while earlier blocks run their step loops).
// launch_bounds(256,2): unified VGPR+AGPR cap 256/wave — the fused peak live
// set (~200) spilled catastrophically at the (256,3) cap of 168.
__global__ __launch_bounds__(256, 2) void k_main(
    const float* __restrict__ A, const u16* __restrict__ Eswz,
    const float* __restrict__ p0,
    const u16* __restrict__ linkImg, const u16* __restrict__ WrImg,
    const u16* __restrict__ WzImg, const u16* __restrict__ WhImg,
    const u16* __restrict__ attW1Img, const u16* __restrict__ outWImg,
    const float* __restrict__ link_b, const float* __restrict__ reset_b,
    const float* __restrict__ update_b, const float* __restrict__ trans_b,
    const float* __restrict__ att_b1, const float* __restrict__ att_W2,
    const float* __restrict__ att_b2, const float* __restrict__ out_b,
    float* __restrict__ atten, float* __restrict__ outPool,
    float* __restrict__ resid)
{
    __shared__ float sAcc[4][16][128];                 // 32 KB (g0 reduction)
    __shared__ float sRs[4][16];
    __shared__ alignas(16) u16 sA[16 * 136], sRP[16 * 136], sP[16 * 136];
    __shared__ float sRed[16];

    int t = threadIdx.x, wid = t >> 6, lane = t & 63, l15 = lane & 15, quad = lane >> 4;
    int bx = blockIdx.x;
    int g = bx >> 8, rmod = bx & 255;
    int b = (rmod & 7) + 8 * g;                        // XCD-affine batch mapping
    int s = (rmod >> 3) & 31;
    size_t r0 = (size_t)b * 512 + (size_t)s * 16;

    // ================= phase G0: acc = A[16 rows] @ E0 (K split across waves)
    {
        const u16* Eb = Eswz + (size_t)b * 262144;
        const float* Ar = A + (r0 + l15) * 2048;
        int kbase = wid * 16;

        f32x4 acc[8];
#pragma unroll
        for (int i = 0; i < 8; i++) acc[i] = (f32x4){0.f, 0.f, 0.f, 0.f};
        float rsum = 0.f;

        float4 xc = *(const float4*)&Ar[kbase * 32 + quad * 8];
        float4 yc = *(const float4*)&Ar[kbase * 32 + quad * 8 + 4];
        bf16x8 bc[8];
#pragma unroll
        for (int tt = 0; tt < 8; tt++) bc[tt] = wfragG(Eb, kbase, tt, l15, quad);

        for (int kc = 0; kc < 16; kc++) {
            int kg = kbase + kc;
            float4 xn, yn; bf16x8 bn[8];
            if (kc < 15) {
                xn = *(const float4*)&Ar[(kg + 1) * 32 + quad * 8];
                yn = *(const float4*)&Ar[(kg + 1) * 32 + quad * 8 + 4];
#pragma unroll
                for (int tt = 0; tt < 8; tt++) bn[tt] = wfragG(Eb, kg + 1, tt, l15, quad);
            }
            rsum += xc.x + xc.y + xc.z + xc.w + yc.x + yc.y + yc.z + yc.w;
            bf16x8 af = cvt8(xc, yc);
#pragma unroll
            for (int tt = 0; tt < 8; tt++) acc[tt] = MFMA16(af, bc[tt], acc[tt]);
            if (kc < 15) {
                xc = xn; yc = yn;
#pragma unroll
                for (int tt = 0; tt < 8; tt++) bc[tt] = bn[tt];
            }
        }
        rsum += __shfl_xor(rsum, 16);
        rsum += __shfl_xor(rsum, 32);
        if (quad == 0) sRs[wid][l15] = rsum;
#pragma unroll
        for (int tt = 0; tt < 8; tt++)
#pragma unroll
            for (int r = 0; r < 4; r++)
                sAcc[wid][quad * 4 + r][tt * 16 + l15] = acc[tt][r];
    }
    __syncthreads();
    // cross-wave reduce -> bf16 G0 straight into sA (step-loop A-operand buffer)
    {
        int row = t >> 4, c8 = (t & 15) * 8;
#pragma unroll
        for (int j = 0; j < 8; j++) {
            float v = sAcc[0][row][c8 + j] + sAcc[1][row][c8 + j] +
                      sAcc[2][row][c8 + j] + sAcc[3][row][c8 + j];
            sA[row * 136 + c8 + j] = f2bf(v);
        }
    }
    if (t < 16) sRed[t] = sRs[0][t] + sRs[1][t] + sRs[2][t] + sRs[3][t];  // rowsum(A)
    __syncthreads();

    // ================= phase steps: 3 GRU steps + attention (row-local)
    int wave = wid;
    int bb = b;
    int ttA = wave * 2, ttB = wave * 2 + 1;
    int colA = ttA * 16 + l15, colB = ttB * 16 + l15;

    // full-K A-operand fragments of a (=G0, from LDS) and p0
    bf16x8 aF[4], pF[4];
#pragma unroll
    for (int kc = 0; kc < 4; kc++) {
        aF[kc] = *(const bf16x8*)&sA[l15 * 136 + kc * 32 + quad * 8];
        float4 x = *(const float4*)&p0[(r0 + l15) * 128 + kc * 32 + quad * 8];
        float4 y = *(const float4*)&p0[(r0 + l15) * 128 + kc * 32 + quad * 8 + 4];
        pF[kc] = cvt8(x, y);
    }
    // own-col fp32 p state (C layout: rows quad*4+r)
    f32x4 pS[2];
#pragma unroll
    for (int j = 0; j < 2; j++)
#pragma unroll
        for (int r = 0; r < 4; r++)
            pS[j][r] = p0[(r0 + quad * 4 + r) * 128 + (wave * 2 + j) * 16 + l15];
    // node part of the residual: sum over this block's 16 rows, own cols
    {
        float s0 = pS[0][0] + pS[0][1] + pS[0][2] + pS[0][3];
        float s1 = pS[1][0] + pS[1][1] + pS[1][2] + pS[1][3];
        s0 += __shfl_xor(s0, 16); s0 += __shfl_xor(s0, 32);
        s1 += __shfl_xor(s1, 16); s1 += __shfl_xor(s1, 32);
        if (quad == 0) {
            atomicAdd(&resid[bb * 128 + colA], s0);
            atomicAdd(&resid[bb * 128 + colB], s1);
        }
    }
    float sv[4];
#pragma unroll
    for (int r = 0; r < 4; r++) sv[r] = sRed[quad * 4 + r];
    float lbA = link_b[colA], lbB = link_b[colB];
    float rbA = reset_b[colA], rbB = reset_b[colB];
    float ubA = update_b[colA], ubB = update_b[colB];
    float tbA = trans_b[colA], tbB = trans_b[colB];

    __syncthreads();                 // sA/sRed reads done before step-loop rewrites
    if (t < 16) sRed[t] = 0.f;       // reused as attention accumulator later

    f32x4 zero4 = {0.f, 0.f, 0.f, 0.f};
    for (int step = 0; step < 3; step++) {
        // ---- phase 1: a_new (own cols) = a @ linkW + rowsum*link_b
        f32x4 cA = zero4, cB = zero4;
#pragma unroll
        for (int kc = 0; kc < 4; kc++) {
            cA = MFMA16(aF[kc], wfragG(linkImg, kc, ttA, l15, quad), cA);
            cB = MFMA16(aF[kc], wfragG(linkImg, kc, ttB, l15, quad), cB);
        }
#pragma unroll
        for (int r = 0; r < 4; r++) {
            sA[(quad * 4 + r) * 136 + colA] = f2bf(cA[r] + sv[r] * lbA);
            sA[(quad * 4 + r) * 136 + colB] = f2bf(cB[r] + sv[r] * lbB);
        }
        __syncthreads();
#pragma unroll
        for (int kc = 0; kc < 4; kc++)
            aF[kc] = *(const bf16x8*)&sA[l15 * 136 + kc * 32 + quad * 8];
        // ---- phase 2: r, z (own cols), K=256 over [a_new, p]
        f32x4 rA = zero4, rB = zero4, zA = zero4, zB = zero4;
#pragma unroll
        for (int kc = 0; kc < 8; kc++) {
            bf16x8 af = (kc < 4) ? aF[kc] : pF[kc - 4];
            rA = MFMA16(af, wfragG(WrImg, kc, ttA, l15, quad), rA);
            rB = MFMA16(af, wfragG(WrImg, kc, ttB, l15, quad), rB);
            zA = MFMA16(af, wfragG(WzImg, kc, ttA, l15, quad), zA);
            zB = MFMA16(af, wfragG(WzImg, kc, ttB, l15, quad), zB);
        }
#pragma unroll
        for (int r = 0; r < 4; r++) {
            float rvA = 1.f / (1.f + __expf(-(rA[r] + rbA)));
            float rvB = 1.f / (1.f + __expf(-(rB[r] + rbB)));
            zA[r] = 1.f / (1.f + __expf(-(zA[r] + ubA)));
            zB[r] = 1.f / (1.f + __expf(-(zB[r] + ubB)));
            sRP[(quad * 4 + r) * 136 + colA] = f2bf(rvA * pS[0][r]);
            sRP[(quad * 4 + r) * 136 + colB] = f2bf(rvB * pS[1][r]);
        }
        __syncthreads();
        bf16x8 rpF[4];
#pragma unroll
        for (int kc = 0; kc < 4; kc++)
            rpF[kc] = *(const bf16x8*)&sRP[l15 * 136 + kc * 32 + quad * 8];
        // ---- phase 3: h (own cols); GRU update (fp32 p state in regs)
        f32x4 hA = zero4, hB = zero4;
#pragma unroll
        for (int kc = 0; kc < 8; kc++) {
            bf16x8 af = (kc < 4) ? aF[kc] : rpF[kc - 4];
            hA = MFMA16(af, wfragG(WhImg, kc, ttA, l15, quad), hA);
            hB = MFMA16(af, wfragG(WhImg, kc, ttB, l15, quad), hB);
        }
#pragma unroll
        for (int r = 0; r < 4; r++) {
            float h1 = tanhf(hA[r] + tbA), h2 = tanhf(hB[r] + tbB);
            pS[0][r] = (1.f - zA[r]) * pS[0][r] + zA[r] * h1;
            pS[1][r] = (1.f - zB[r]) * pS[1][r] + zB[r] * h2;
            sP[(quad * 4 + r) * 136 + colA] = f2bf(pS[0][r]);
            sP[(quad * 4 + r) * 136 + colB] = f2bf(pS[1][r]);
        }
        __syncthreads();
#pragma unroll
        for (int kc = 0; kc < 4; kc++)
            pF[kc] = *(const bf16x8*)&sP[l15 * 136 + kc * 32 + quad * 8];
    }
    // ---- attention + out (own cols), A-operand = p3 fragments
    f32x4 atA = zero4, atB = zero4, oA = zero4, oB = zero4;
#pragma unroll
    for (int kc = 0; kc < 4; kc++) {
        atA = MFMA16(pF[kc], wfragG(attW1Img, kc, ttA, l15, quad), atA);
        atB = MFMA16(pF[kc], wfragG(attW1Img, kc, ttB, l15, quad), atB);
        oA  = MFMA16(pF[kc], wfragG(outWImg,  kc, ttA, l15, quad), oA);
        oB  = MFMA16(pF[kc], wfragG(outWImg,  kc, ttB, l15, quad), oB);
    }
    float b1A = att_b1[colA], b1B = att_b1[colB];
    float w2A = att_W2[colA], w2B = att_W2[colB];
    float obA = out_b[colA],  obB = out_b[colB];
    float pr[4];
#pragma unroll
    for (int r = 0; r < 4; r++) {
        pr[r] = tanhf(atA[r] + b1A) * w2A + tanhf(atB[r] + b1B) * w2B;
        outPool[(r0 + quad * 4 + r) * 128 + colA] = tanhf(oA[r] + obA);
        outPool[(r0 + quad * 4 + r) * 128 + colB] = tanhf(oB[r] + obB);
    }
#pragma unroll
    for (int r = 0; r < 4; r++) {
        float v = pr[r];
        v += __shfl_xor(v, 1); v += __shfl_xor(v, 2);
        v += __shfl_xor(v, 4); v += __shfl_xor(v, 8);
        if (l15 == 0) atomicAdd(&sRed[quad * 4 + r], v);
    }
    __syncthreads();
    if (t < 16) atten[r0 + t] = sRed[t] + att_b2[0];
}

// ---------------------------------------------------------------- edges out: E0@W3 + ebias
__global__ __launch_bounds__(64) void k_eout(
    const float* __restrict__ E0, const u16* __restrict__ W3Img,
    const float* __restrict__ ebias, float* __restrict__ Eout)
{
    int t = threadIdx.x, l15 = t & 15, quad = t >> 4;
    size_t r0 = (size_t)blockIdx.x * 16;
    bf16x8 eF[4];
#pragma unroll
    for (int kc = 0; kc < 4; kc++) {
        float4 x = *(const float4*)&E0[(r0 + l15) * 128 + kc * 32 + quad * 8];
        float4 y = *(const float4*)&E0[(r0 + l15) * 128 + kc * 32 + quad * 8 + 4];
        eF[kc] = cvt8(x, y);
    }
    f32x4 acc[8];
#pragma unroll
    for (int i = 0; i < 8; i++) acc[i] = (f32x4){0.f, 0.f, 0.f, 0.f};
    {
        bf16x8 wc[8], wn[8];
#pragma unroll
        for (int tt = 0; tt < 8; tt++) wc[tt] = wfragG(W3Img, 0, tt, l15, quad);
#pragma unroll
        for (int kc = 0; kc < 4; kc++) {
            if (kc < 3)
#pragma unroll
                for (int tt = 0; tt < 8; tt++) wn[tt] = wfragG(W3Img, kc + 1, tt, l15, quad);
#pragma unroll
            for (int tt = 0; tt < 8; tt++) acc[tt] = MFMA16(eF[kc], wc[tt], acc[tt]);
            if (kc < 3)
#pragma unroll
                for (int tt = 0; tt < 8; tt++) wc[tt] = wn[tt];
        }
    }
#pragma unroll
    for (int tt = 0; tt < 8; tt++) {
        int col = tt * 16 + l15; float eb = ebias[col];
#pragma unroll
        for (int r = 0; r < 4; r++)
            Eout[(r0 + quad * 4 + r) * 128 + col] = acc[tt][r] + eb;
    }
}

// ---------------------------------------------------------------- softmax-pool + residual
__global__ __launch_bounds__(512) void k_fin(
    const float* __restrict__ atten, const float* __restrict__ outPool,
    const float* __restrict__ resid,
    float* __restrict__ outRes, float* __restrict__ outMul)
{
    __shared__ float swv[512];
    __shared__ float sred[512];
    __shared__ float sacc[4][128];
    int t = threadIdx.x, b = blockIdx.x;
    float a = atten[b * 512 + t];
    sred[t] = a; __syncthreads();
    for (int s = 256; s > 0; s >>= 1) { if (t < s) sred[t] = fmaxf(sred[t], sred[t + s]); __syncthreads(); }
    float mx = sred[0]; __syncthreads();
    float e = __expf(a - mx);
    swv[t] = e; sred[t] = e; __syncthreads();
    for (int s = 256; s > 0; s >>= 1) { if (t < s) sred[t] += sred[t + s]; __syncthreads(); }
    float Z = sred[0]; __syncthreads();
    int col = t & 127, q = t >> 7;
    const float* op = outPool + ((size_t)b * 512 + q * 128) * 128 + col;
    float accM = 0.f;
#pragma unroll 8
    for (int n = 0; n < 128; n++) accM += swv[q * 128 + n] * op[(size_t)n * 128];
    sacc[q][col] = accM;
    __syncthreads();
    if (t < 128) {
        float mulv = (sacc[0][t] + sacc[1][t] + sacc[2][t] + sacc[3][t]) / Z;
        float rv = resid[b * 128 + t] * (1.f / 2560.f);
        outMul[b * 128 + t] = mulv;
        outRes[b * 128 + t] = fmaxf(0.f, tanhf(mulv) + rv);
    }
}

// ================================================================ launch
extern "C" void kernel_launch(void* const* d_in, const int* in_sizes, int n_in,
                              void* d_out, int out_size, void* d_ws, size_t ws_size,
                              hipStream_t stream)
{
    const float* prop0  = (const float*)d_in[0];
    const float* edge0  = (const float*)d_in[1];
    const float* Amat   = (const float*)d_in[2];
    const float* linkW  = (const float*)d_in[4];
    const float* linkb  = (const float*)d_in[5];
    const float* resetW = (const float*)d_in[6];
    const float* resetb = (const float*)d_in[7];
    const float* updateW= (const float*)d_in[8];
    const float* updateb= (const float*)d_in[9];
    const float* transW = (const float*)d_in[10];
    const float* transb = (const float*)d_in[11];
    const float* attW1  = (const float*)d_in[12];
    const float* attb1  = (const float*)d_in[13];
    const float* attW2  = (const float*)d_in[14];
    const float* attb2  = (const float*)d_in[15];
    const float* outW   = (const float*)d_in[16];
    const float* outb   = (const float*)d_in[17];

    char* w = (char*)d_ws;
    u16*   ws_a_bf    = (u16*)(w);                    // (unused after R5 fusion)
    float* ws_rowsum  = (float*)(w + 4194304);        // (unused after R5 fusion)
    float* ws_atten   = (float*)(w + 4259840);        //    65,536 B
    float* ws_resid   = (float*)(w + 4325376);        //    16,384 B
    float* ws_W2      = (float*)(w + 4341760);        //    65,536 B
    float* ws_ebias   = (float*)(w + 4407296);        //       512 B
    u16*   ws_linkImg = (u16*)(w + 4407808);          //    32,768 B
    u16*   ws_W3Img   = (u16*)(w + 4440576);          //    32,768 B
    u16*   ws_WrImg   = (u16*)(w + 4473344);          //    65,536 B
    u16*   ws_WzImg   = (u16*)(w + 4538880);          //    65,536 B
    u16*   ws_WhImg   = (u16*)(w + 4604416);          //    65,536 B
    u16*   ws_attW1Img= (u16*)(w + 4669952);          //    32,768 B
    u16*   ws_outWImg = (u16*)(w + 4702720);          //    32,768 B (~4.7 MB)
    (void)ws_a_bf; (void)ws_rowsum;

    float* out_res  = (float*)d_out;
    float* out_mul  = out_res + 4096;
    float* out_edge = out_res + 8192;
    // Scratch inside d_out edge region (dead until k_eout, which runs last):
    u16*   Eswz     = (u16*)out_edge;                 // 16.78 MB
    float* outPool  = out_edge + 4194304;             // next 8.39 MB

    hipMemsetAsync(ws_resid, 0, 32 * 128 * sizeof(float), stream);
    k_prep1<<<274, 256, 0, stream>>>(linkW, resetW, updateW, transW, attW1, outW,
                                     ws_W2, ws_linkImg, ws_WrImg, ws_WzImg, ws_WhImg,
                                     ws_attW1Img, ws_outWImg);
    k_prep2<<<257, 256, 0, stream>>>(linkW, linkb, ws_W2, ws_W3Img, ws_ebias);
    k_te<<<dim3(64, 32), 256, 0, stream>>>(edge0, Eswz, ws_resid);
    k_main<<<1024, 256, 0, stream>>>(Amat, Eswz, prop0,
                                     ws_linkImg, ws_WrImg, ws_WzImg, ws_WhImg,
                                     ws_attW1Img, ws_outWImg,
                                     linkb, resetb, updateb, transb,
                                     attb1, attW2, attb2, outb,
                                     ws_atten, outPool, ws_resid);
    k_fin<<<32, 512, 0, stream>>>(ws_atten, outPool, ws_resid, out_res, out_mul);
    k_eout<<<4096, 64, 0, stream>>>(edge0, ws_W3Img, ws_ebias, out_edge);
}

// Round 3
// 376.564 us; speedup vs baseline: 1.3004x; 1.1092x over previous
//
#include <hip/hip_runtime.h>
#include <hip/hip_bf16.h>

// SpatialRelation on MI355X — round 7.
// R5/R6 post-mortem: fused k_main spilled (WRITE_SIZE 201/107 MB vs 9 MB
// ideal). Cause: fully-unrolled step-phase loops expose 32 independent
// global wfragG loads -> scheduler builds a 128-reg load window on top of
// ~80 regs of operand arrays (aF/pF/rpF) -> peak > 256 cap.
// R7: operands read DIRECTLY from LDS inside rolled loops (#pragma unroll 2)
// via one combined sBuf[48][136] (rows 0-15 a | 16-31 p | 32-47 r*p).
// No register operand arrays, load window <= ~10. Peak regs ~= G0's ~160.

typedef unsigned short u16;
typedef __attribute__((ext_vector_type(4))) float f32x4;
typedef __attribute__((ext_vector_type(8))) short bf16x8;

#define DI static __device__ __forceinline__

DI u16 f2bf(float f) {
    unsigned u = __builtin_bit_cast(unsigned, f);
    return (u16)((u + 0x7fffu + ((u >> 16) & 1u)) >> 16);  // RNE
}

DI bf16x8 cvt8(float4 a, float4 b) {
    u16 tmp[8] = {f2bf(a.x), f2bf(a.y), f2bf(a.z), f2bf(a.w),
                  f2bf(b.x), f2bf(b.y), f2bf(b.z), f2bf(b.w)};
    return *(const bf16x8*)tmp;
}

// B-operand image: element (k,n) at (((k>>5)*128+n)*4 + (((k>>3)&3)^((n>>1)&3)))*8 + (k&7)
DI int imgIdx(int k, int n) {
    return (((k >> 5) * 128 + n) * 4 + (((k >> 3) & 3) ^ ((n >> 1) & 3))) * 8 + (k & 7);
}
// B fragment (16B) direct from a weight/edge image in global memory.
DI bf16x8 wfragG(const u16* __restrict__ img, int kc, int tt, int l15, int quad) {
    return *(const bf16x8*)&img[(((kc * 128 + tt * 16 + l15) * 4) + (quad ^ ((l15 >> 1) & 3))) * 8];
}

#define MFMA16(a, b, c) __builtin_amdgcn_mfma_f32_16x16x32_bf16(a, b, c, 0, 0, 0)

// ---------------------------------------------------------------- prep 1
__global__ __launch_bounds__(256) void k_prep1(
    const float* __restrict__ linkW, const float* __restrict__ resetW,
    const float* __restrict__ updateW, const float* __restrict__ transW,
    const float* __restrict__ attW1, const float* __restrict__ outW,
    float* __restrict__ W2, u16* __restrict__ linkImg, u16* __restrict__ WrImg,
    u16* __restrict__ WzImg, u16* __restrict__ WhImg, u16* __restrict__ attW1Img,
    u16* __restrict__ outWImg)
{
    int blk = blockIdx.x, t = threadIdx.x;
    if (blk < 256) {
        int idx = blk * 256 + t;
        int out = idx >> 2, q = idx & 3;
        int r = out >> 7, c = out & 127;
        const float* ar = linkW + r * 128 + q * 32;
        float acc = 0.f;
#pragma unroll
        for (int k = 0; k < 32; k++) acc += ar[k] * linkW[(q * 32 + k) * 128 + c];
        acc += __shfl_xor(acc, 1);
        acc += __shfl_xor(acc, 2);
        if (q == 0) W2[out] = acc;
    } else {
        const float* src; u16* dst; int base;
        if (blk < 260)      { src = resetW;  dst = WrImg;    base = 256; }
        else if (blk < 264) { src = updateW; dst = WzImg;    base = 260; }
        else if (blk < 268) { src = transW;  dst = WhImg;    base = 264; }
        else if (blk < 270) { src = linkW;   dst = linkImg;  base = 268; }
        else if (blk < 272) { src = attW1;   dst = attW1Img; base = 270; }
        else                { src = outW;    dst = outWImg;  base = 272; }
        int off = (blk - base) * 8192;
        for (int i = 0; i < 32; i++) {
            int e = off + t + i * 256;
            int k = e >> 7, n = e & 127;
            dst[imgIdx(k, n)] = f2bf(src[e]);
        }
    }
}

// ---------------------------------------------------------------- prep 2
__global__ __launch_bounds__(256) void k_prep2(
    const float* __restrict__ linkW, const float* __restrict__ linkb,
    const float* __restrict__ W2, u16* __restrict__ W3Img, float* __restrict__ ebias)
{
    int blk = blockIdx.x, t = threadIdx.x;
    if (blk < 256) {
        int idx = blk * 256 + t;
        int out = idx >> 2, q = idx & 3;
        int r = out >> 7, c = out & 127;
        const float* ar = W2 + r * 128 + q * 32;
        float acc = 0.f;
#pragma unroll
        for (int k = 0; k < 32; k++) acc += ar[k] * linkW[(q * 32 + k) * 128 + c];
        acc += __shfl_xor(acc, 1);
        acc += __shfl_xor(acc, 2);
        if (q == 0) W3Img[imgIdx(r, c)] = f2bf(acc);
    } else if (t < 128) {
        float acc = linkb[t];
#pragma unroll 8
        for (int k = 0; k < 128; k++) acc += linkb[k] * (W2[k * 128 + t] + linkW[k * 128 + t]);
        ebias[t] = acc;
    }
}

// ---------------------------------------------------------------- E transpose (+edge resid)
__global__ __launch_bounds__(256) void k_te(
    const float* __restrict__ E0, u16* __restrict__ Eswz, float* __restrict__ resid)
{
    __shared__ alignas(16) u16 sT[4096];
    __shared__ float sCol[128];
    int t = threadIdx.x, kc = blockIdx.x, b = blockIdx.y;
    const float* Eb = E0 + (size_t)b * 262144 + (size_t)kc * 32 * 128;
    if (t < 128) sCol[t] = 0.f;
    float part[4] = {0.f, 0.f, 0.f, 0.f};
    int ncol = (t & 31) * 4;
    for (int i = 0; i < 4; i++) {
        int f4i = t + i * 256;
        int k5 = f4i >> 5;
        float4 v = *(const float4*)&Eb[k5 * 128 + ncol];
        int g = k5 >> 3, o = k5 & 7;
        float vv[4] = {v.x, v.y, v.z, v.w};
#pragma unroll
        for (int j = 0; j < 4; j++) {
            int n = ncol + j;
            sT[(n * 4 + (g ^ ((n >> 1) & 3))) * 8 + o] = f2bf(vv[j]);
            part[j] += vv[j];
        }
    }
    __syncthreads();
#pragma unroll
    for (int j = 0; j < 4; j++) atomicAdd(&sCol[ncol + j], part[j]);
    u16* dst = Eswz + (size_t)b * 262144 + (size_t)kc * 4096;
    ((uint4*)dst)[t] = ((const uint4*)sT)[t];
    ((uint4*)dst)[t + 256] = ((const uint4*)sT)[t + 256];
    __syncthreads();
    if (t < 128) atomicAdd(&resid[b * 128 + t], sCol[t]);
}

// ---------------------------------------------------------------- FUSED: G0 = A@E0, then
// all 3 GRU steps + attention. Operand fragments for the step loop live in
// sBuf (rows 0-15 = a, 16-31 = p, 32-47 = r*p) and are ds_read_b128-loaded
// inside #pragma-unroll-2 loops — no register operand arrays, bounded global
// load windows => no spills at the (256,2) unified cap of 256.
__global__ __launch_bounds__(256, 2) void k_main(
    const float* __restrict__ A, const u16* __restrict__ Eswz,
    const float* __restrict__ p0,
    const u16* __restrict__ linkImg, const u16* __restrict__ WrImg,
    const u16* __restrict__ WzImg, const u16* __restrict__ WhImg,
    const u16* __restrict__ attW1Img, const u16* __restrict__ outWImg,
    const float* __restrict__ link_b, const float* __restrict__ reset_b,
    const float* __restrict__ update_b, const float* __restrict__ trans_b,
    const float* __restrict__ att_b1, const float* __restrict__ att_W2,
    const float* __restrict__ att_b2, const float* __restrict__ out_b,
    float* __restrict__ atten, float* __restrict__ outPool,
    float* __restrict__ resid)
{
    __shared__ float sAcc[4][16][128];                 // 32 KB (G0 reduction only)
    __shared__ float sRs[4][16];
    __shared__ alignas(16) u16 sBuf[48 * 136];         // 12.75 KB operand buffer
    __shared__ float sRed[16];

    int t = threadIdx.x, wid = t >> 6, lane = t & 63, l15 = lane & 15, quad = lane >> 4;
    int bx = blockIdx.x;
    int g = bx >> 8, rmod = bx & 255;
    int b = (rmod & 7) + 8 * g;                        // XCD-affine batch mapping
    int s = (rmod >> 3) & 31;
    size_t r0 = (size_t)b * 512 + (size_t)s * 16;

    // ================= phase G0: acc = A[16 rows] @ E0 (K split across waves)
    {
        const u16* Eb = Eswz + (size_t)b * 262144;
        const float* Ar = A + (r0 + l15) * 2048;
        int kbase = wid * 16;

        f32x4 acc[8];
#pragma unroll
        for (int i = 0; i < 8; i++) acc[i] = (f32x4){0.f, 0.f, 0.f, 0.f};
        float rsum = 0.f;

        float4 xc = *(const float4*)&Ar[kbase * 32 + quad * 8];
        float4 yc = *(const float4*)&Ar[kbase * 32 + quad * 8 + 4];
        bf16x8 bc[8];
#pragma unroll
        for (int tt = 0; tt < 8; tt++) bc[tt] = wfragG(Eb, kbase, tt, l15, quad);

        for (int kc = 0; kc < 16; kc++) {
            int kg = kbase + kc;
            float4 xn, yn; bf16x8 bn[8];
            if (kc < 15) {
                xn = *(const float4*)&Ar[(kg + 1) * 32 + quad * 8];
                yn = *(const float4*)&Ar[(kg + 1) * 32 + quad * 8 + 4];
#pragma unroll
                for (int tt = 0; tt < 8; tt++) bn[tt] = wfragG(Eb, kg + 1, tt, l15, quad);
            }
            rsum += xc.x + xc.y + xc.z + xc.w + yc.x + yc.y + yc.z + yc.w;
            bf16x8 af = cvt8(xc, yc);
#pragma unroll
            for (int tt = 0; tt < 8; tt++) acc[tt] = MFMA16(af, bc[tt], acc[tt]);
            if (kc < 15) {
                xc = xn; yc = yn;
#pragma unroll
                for (int tt = 0; tt < 8; tt++) bc[tt] = bn[tt];
            }
        }
        rsum += __shfl_xor(rsum, 16);
        rsum += __shfl_xor(rsum, 32);
        if (quad == 0) sRs[wid][l15] = rsum;
#pragma unroll
        for (int tt = 0; tt < 8; tt++)
#pragma unroll
            for (int r = 0; r < 4; r++)
                sAcc[wid][quad * 4 + r][tt * 16 + l15] = acc[tt][r];
    }
    __syncthreads();
    // cross-wave reduce -> bf16 G0 into sBuf rows 0-15; stage p0 -> rows 16-31
    {
        int row = t >> 4, c8 = (t & 15) * 8;
        u16 o[8];
#pragma unroll
        for (int j = 0; j < 8; j++) {
            float v = sAcc[0][row][c8 + j] + sAcc[1][row][c8 + j] +
                      sAcc[2][row][c8 + j] + sAcc[3][row][c8 + j];
            o[j] = f2bf(v);
        }
        *(uint4*)&sBuf[row * 136 + c8] = *(const uint4*)o;
        float4 x = *(const float4*)&p0[(r0 + row) * 128 + c8];
        float4 y = *(const float4*)&p0[(r0 + row) * 128 + c8 + 4];
        bf16x8 pv = cvt8(x, y);
        *(bf16x8*)&sBuf[(16 + row) * 136 + c8] = pv;
    }
    if (t < 16) sRed[t] = sRs[0][t] + sRs[1][t] + sRs[2][t] + sRs[3][t];  // rowsum(A)
    __syncthreads();

    // ================= phase steps: 3 GRU steps + attention (row-local)
    int ttA = wid * 2, ttB = wid * 2 + 1;              // this wave's column tiles
    int colA = ttA * 16 + l15, colB = ttB * 16 + l15;

    // own-col fp32 p state (C layout: rows quad*4+r)
    f32x4 pS[2];
#pragma unroll
    for (int j = 0; j < 2; j++)
#pragma unroll
        for (int r = 0; r < 4; r++)
            pS[j][r] = p0[(r0 + quad * 4 + r) * 128 + (wid * 2 + j) * 16 + l15];
    // node part of the residual: sum over this block's 16 rows, own cols
    {
        float s0 = pS[0][0] + pS[0][1] + pS[0][2] + pS[0][3];
        float s1 = pS[1][0] + pS[1][1] + pS[1][2] + pS[1][3];
        s0 += __shfl_xor(s0, 16); s0 += __shfl_xor(s0, 32);
        s1 += __shfl_xor(s1, 16); s1 += __shfl_xor(s1, 32);
        if (quad == 0) {
            atomicAdd(&resid[b * 128 + colA], s0);
            atomicAdd(&resid[b * 128 + colB], s1);
        }
    }
    float sv[4];
#pragma unroll
    for (int r = 0; r < 4; r++) sv[r] = sRed[quad * 4 + r];
    float lbA = link_b[colA], lbB = link_b[colB];
    float rbA = reset_b[colA], rbB = reset_b[colB];
    float ubA = update_b[colA], ubB = update_b[colB];
    float tbA = trans_b[colA], tbB = trans_b[colB];

    __syncthreads();                 // all sRed (rowsum) reads done
    if (t < 16) sRed[t] = 0.f;       // reused as attention accumulator later

    f32x4 zero4 = {0.f, 0.f, 0.f, 0.f};
    int fcol = quad * 8;             // fragment byte-col base (u16 units)
    for (int step = 0; step < 3; step++) {
        // ---- phase 1: a_new (own cols) = a @ linkW + rowsum*link_b
        f32x4 cA = zero4, cB = zero4;
#pragma unroll 2
        for (int kc = 0; kc < 4; kc++) {
            bf16x8 af = *(const bf16x8*)&sBuf[l15 * 136 + kc * 32 + fcol];
            cA = MFMA16(af, wfragG(linkImg, kc, ttA, l15, quad), cA);
            cB = MFMA16(af, wfragG(linkImg, kc, ttB, l15, quad), cB);
        }
        __syncthreads();             // all reads of rows 0-15 done before rewrite
#pragma unroll
        for (int r = 0; r < 4; r++) {
            sBuf[(quad * 4 + r) * 136 + colA] = f2bf(cA[r] + sv[r] * lbA);
            sBuf[(quad * 4 + r) * 136 + colB] = f2bf(cB[r] + sv[r] * lbB);
        }
        __syncthreads();             // a_new visible
        // ---- phase 2: r, z (own cols), K=256 over [a_new(rows 0-15), p(rows 16-31)]
        f32x4 rA = zero4, rB = zero4, zA = zero4, zB = zero4;
#pragma unroll 2
        for (int kc = 0; kc < 8; kc++) {
            int row = ((kc >> 2) * 16 + l15) * 136 + (kc & 3) * 32 + fcol;
            bf16x8 af = *(const bf16x8*)&sBuf[row];
            rA = MFMA16(af, wfragG(WrImg, kc, ttA, l15, quad), rA);
            rB = MFMA16(af, wfragG(WrImg, kc, ttB, l15, quad), rB);
            zA = MFMA16(af, wfragG(WzImg, kc, ttA, l15, quad), zA);
            zB = MFMA16(af, wfragG(WzImg, kc, ttB, l15, quad), zB);
        }
#pragma unroll
        for (int r = 0; r < 4; r++) {
            float rvA = 1.f / (1.f + __expf(-(rA[r] + rbA)));
            float rvB = 1.f / (1.f + __expf(-(rB[r] + rbB)));
            zA[r] = 1.f / (1.f + __expf(-(zA[r] + ubA)));
            zB[r] = 1.f / (1.f + __expf(-(zB[r] + ubB)));
            sBuf[(32 + quad * 4 + r) * 136 + colA] = f2bf(rvA * pS[0][r]);
            sBuf[(32 + quad * 4 + r) * 136 + colB] = f2bf(rvB * pS[1][r]);
        }
        __syncthreads();             // r*p (rows 32-47) visible
        // ---- phase 3: h (own cols), K=256 over [a_new(rows 0-15), r*p(rows 32-47)]
        f32x4 hA = zero4, hB = zero4;
#pragma unroll 2
        for (int kc = 0; kc < 8; kc++) {
            int row = ((kc >> 2) * 32 + l15) * 136 + (kc & 3) * 32 + fcol;
            bf16x8 af = *(const bf16x8*)&sBuf[row];
            hA = MFMA16(af, wfragG(WhImg, kc, ttA, l15, quad), hA);
            hB = MFMA16(af, wfragG(WhImg, kc, ttB, l15, quad), hB);
        }
#pragma unroll
        for (int r = 0; r < 4; r++) {
            float h1 = tanhf(hA[r] + tbA), h2 = tanhf(hB[r] + tbB);
            pS[0][r] = (1.f - zA[r]) * pS[0][r] + zA[r] * h1;
            pS[1][r] = (1.f - zB[r]) * pS[1][r] + zB[r] * h2;
            sBuf[(16 + quad * 4 + r) * 136 + colA] = f2bf(pS[0][r]);
            sBuf[(16 + quad * 4 + r) * 136 + colB] = f2bf(pS[1][r]);
        }
        __syncthreads();             // p (rows 16-31) visible for next step / attention
    }
    // ---- attention + out (own cols), A-operand = p3 (rows 16-31)
    f32x4 atA = zero4, atB = zero4, oA = zero4, oB = zero4;
#pragma unroll 2
    for (int kc = 0; kc < 4; kc++) {
        bf16x8 pf = *(const bf16x8*)&sBuf[(16 + l15) * 136 + kc * 32 + fcol];
        atA = MFMA16(pf, wfragG(attW1Img, kc, ttA, l15, quad), atA);
        atB = MFMA16(pf, wfragG(attW1Img, kc, ttB, l15, quad), atB);
        oA  = MFMA16(pf, wfragG(outWImg,  kc, ttA, l15, quad), oA);
        oB  = MFMA16(pf, wfragG(outWImg,  kc, ttB, l15, quad), oB);
    }
    float b1A = att_b1[colA], b1B = att_b1[colB];
    float w2A = att_W2[colA], w2B = att_W2[colB];
    float obA = out_b[colA],  obB = out_b[colB];
    float pr[4];
#pragma unroll
    for (int r = 0; r < 4; r++) {
        pr[r] = tanhf(atA[r] + b1A) * w2A + tanhf(atB[r] + b1B) * w2B;
        outPool[(r0 + quad * 4 + r) * 128 + colA] = tanhf(oA[r] + obA);
        outPool[(r0 + quad * 4 + r) * 128 + colB] = tanhf(oB[r] + obB);
    }
#pragma unroll
    for (int r = 0; r < 4; r++) {
        float v = pr[r];
        v += __shfl_xor(v, 1); v += __shfl_xor(v, 2);
        v += __shfl_xor(v, 4); v += __shfl_xor(v, 8);
        if (l15 == 0) atomicAdd(&sRed[quad * 4 + r], v);
    }
    __syncthreads();
    if (t < 16) atten[r0 + t] = sRed[t] + att_b2[0];
}

// ---------------------------------------------------------------- edges out: E0@W3 + ebias
__global__ __launch_bounds__(64) void k_eout(
    const float* __restrict__ E0, const u16* __restrict__ W3Img,
    const float* __restrict__ ebias, float* __restrict__ Eout)
{
    int t = threadIdx.x, l15 = t & 15, quad = t >> 4;
    size_t r0 = (size_t)blockIdx.x * 16;
    bf16x8 eF[4];
#pragma unroll
    for (int kc = 0; kc < 4; kc++) {
        float4 x = *(const float4*)&E0[(r0 + l15) * 128 + kc * 32 + quad * 8];
        float4 y = *(const float4*)&E0[(r0 + l15) * 128 + kc * 32 + quad * 8 + 4];
        eF[kc] = cvt8(x, y);
    }
    f32x4 acc[8];
#pragma unroll
    for (int i = 0; i < 8; i++) acc[i] = (f32x4){0.f, 0.f, 0.f, 0.f};
    {
        bf16x8 wc[8], wn[8];
#pragma unroll
        for (int tt = 0; tt < 8; tt++) wc[tt] = wfragG(W3Img, 0, tt, l15, quad);
#pragma unroll
        for (int kc = 0; kc < 4; kc++) {
            if (kc < 3)
#pragma unroll
                for (int tt = 0; tt < 8; tt++) wn[tt] = wfragG(W3Img, kc + 1, tt, l15, quad);
#pragma unroll
            for (int tt = 0; tt < 8; tt++) acc[tt] = MFMA16(eF[kc], wc[tt], acc[tt]);
            if (kc < 3)
#pragma unroll
                for (int tt = 0; tt < 8; tt++) wc[tt] = wn[tt];
        }
    }
#pragma unroll
    for (int tt = 0; tt < 8; tt++) {
        int col = tt * 16 + l15; float eb = ebias[col];
#pragma unroll
        for (int r = 0; r < 4; r++)
            Eout[(r0 + quad * 4 + r) * 128 + col] = acc[tt][r] + eb;
    }
}

// ---------------------------------------------------------------- softmax-pool + residual
__global__ __launch_bounds__(512) void k_fin(
    const float* __restrict__ atten, const float* __restrict__ outPool,
    const float* __restrict__ resid,
    float* __restrict__ outRes, float* __restrict__ outMul)
{
    __shared__ float swv[512];
    __shared__ float sred[512];
    __shared__ float sacc[4][128];
    int t = threadIdx.x, b = blockIdx.x;
    float a = atten[b * 512 + t];
    sred[t] = a; __syncthreads();
    for (int s = 256; s > 0; s >>= 1) { if (t < s) sred[t] = fmaxf(sred[t], sred[t + s]); __syncthreads(); }
    float mx = sred[0]; __syncthreads();
    float e = __expf(a - mx);
    swv[t] = e; sred[t] = e; __syncthreads();
    for (int s = 256; s > 0; s >>= 1) { if (t < s) sred[t] += sred[t + s]; __syncthreads(); }
    float Z = sred[0]; __syncthreads();
    int col = t & 127, q = t >> 7;
    const float* op = outPool + ((size_t)b * 512 + q * 128) * 128 + col;
    float accM = 0.f;
#pragma unroll 8
    for (int n = 0; n < 128; n++) accM += swv[q * 128 + n] * op[(size_t)n * 128];
    sacc[q][col] = accM;
    __syncthreads();
    if (t < 128) {
        float mulv = (sacc[0][t] + sacc[1][t] + sacc[2][t] + sacc[3][t]) / Z;
        float rv = resid[b * 128 + t] * (1.f / 2560.f);
        outMul[b * 128 + t] = mulv;
        outRes[b * 128 + t] = fmaxf(0.f, tanhf(mulv) + rv);
    }
}

// ================================================================ launch
extern "C" void kernel_launch(void* const* d_in, const int* in_sizes, int n_in,
                              void* d_out, int out_size, void* d_ws, size_t ws_size,
                              hipStream_t stream)
{
    const float* prop0  = (const float*)d_in[0];
    const float* edge0  = (const float*)d_in[1];
    const float* Amat   = (const float*)d_in[2];
    const float* linkW  = (const float*)d_in[4];
    const float* linkb  = (const float*)d_in[5];
    const float* resetW = (const float*)d_in[6];
    const float* resetb = (const float*)d_in[7];
    const float* updateW= (const float*)d_in[8];
    const float* updateb= (const float*)d_in[9];
    const float* transW = (const float*)d_in[10];
    const float* transb = (const float*)d_in[11];
    const float* attW1  = (const float*)d_in[12];
    const float* attb1  = (const float*)d_in[13];
    const float* attW2  = (const float*)d_in[14];
    const float* attb2  = (const float*)d_in[15];
    const float* outW   = (const float*)d_in[16];
    const float* outb   = (const float*)d_in[17];

    char* w = (char*)d_ws;
    float* ws_atten   = (float*)(w + 4259840);        //    65,536 B
    float* ws_resid   = (float*)(w + 4325376);        //    16,384 B
    float* ws_W2      = (float*)(w + 4341760);        //    65,536 B
    float* ws_ebias   = (float*)(w + 4407296);        //       512 B
    u16*   ws_linkImg = (u16*)(w + 4407808);          //    32,768 B
    u16*   ws_W3Img   = (u16*)(w + 4440576);          //    32,768 B
    u16*   ws_WrImg   = (u16*)(w + 4473344);          //    65,536 B
    u16*   ws_WzImg   = (u16*)(w + 4538880);          //    65,536 B
    u16*   ws_WhImg   = (u16*)(w + 4604416);          //    65,536 B
    u16*   ws_attW1Img= (u16*)(w + 4669952);          //    32,768 B
    u16*   ws_outWImg = (u16*)(w + 4702720);          //    32,768 B (~4.7 MB)

    float* out_res  = (float*)d_out;
    float* out_mul  = out_res + 4096;
    float* out_edge = out_res + 8192;
    // Scratch inside d_out edge region (dead until k_eout, which runs last):
    u16*   Eswz     = (u16*)out_edge;                 // 16.78 MB
    float* outPool  = out_edge + 4194304;             // next 8.39 MB

    hipMemsetAsync(ws_resid, 0, 32 * 128 * sizeof(float), stream);
    k_prep1<<<274, 256, 0, stream>>>(linkW, resetW, updateW, transW, attW1, outW,
                                     ws_W2, ws_linkImg, ws_WrImg, ws_WzImg, ws_WhImg,
                                     ws_attW1Img, ws_outWImg);
    k_prep2<<<257, 256, 0, stream>>>(linkW, linkb, ws_W2, ws_W3Img, ws_ebias);
    k_te<<<dim3(64, 32), 256, 0, stream>>>(edge0, Eswz, ws_resid);
    k_main<<<1024, 256, 0, stream>>>(Amat, Eswz, prop0,
                                     ws_linkImg, ws_WrImg, ws_WzImg, ws_WhImg,
                                     ws_attW1Img, ws_outWImg,
                                     linkb, resetb, updateb, transb,
                                     attb1, attW2, attb2, outb,
                                     ws_atten, outPool, ws_resid);
    k_fin<<<32, 512, 0, stream>>>(ws_atten, outPool, ws_resid, out_res, out_mul);
    k_eout<<<4096, 64, 0, stream>>>(edge0, ws_W3Img, ws_ebias, out_edge);
}

// Round 4
// 369.433 us; speedup vs baseline: 1.3255x; 1.0193x over previous
//
#include <hip/hip_runtime.h>
#include <hip/hip_bf16.h>

// SpatialRelation on MI355X — round 8.
// R7 fixed the spills (WRITE 8.8MB) but k_main is latency-bound: MfmaUtil
// 6.4%, VALU 18%, HBM 9%, Occupancy 25% (2 of the 4 available blocks/CU
// resident; 46.6KB LDS + G0 regs at the (256,2) allocation are the gate).
// R8: G0 restructured as 2x2 (tt-group x K-half) wave split:
//  - acc[4] not acc[8]; 4-frag not 8-frag prefetch window (-32 regs peak)
//  - pairwise reduction via 8.3KB LDS (was 32KB 4-wave fp32 buffer)
//  - K-half-1 waves stage p0 while K-half-0 waves combine (was serial)
//  - LDS 46.6KB -> 21.6KB; __launch_bounds__(256,4) => 4 blocks/CU resident.

typedef unsigned short u16;
typedef __attribute__((ext_vector_type(4))) float f32x4;
typedef __attribute__((ext_vector_type(8))) short bf16x8;

#define DI static __device__ __forceinline__

DI u16 f2bf(float f) {
    unsigned u = __builtin_bit_cast(unsigned, f);
    return (u16)((u + 0x7fffu + ((u >> 16) & 1u)) >> 16);  // RNE
}

DI bf16x8 cvt8(float4 a, float4 b) {
    u16 tmp[8] = {f2bf(a.x), f2bf(a.y), f2bf(a.z), f2bf(a.w),
                  f2bf(b.x), f2bf(b.y), f2bf(b.z), f2bf(b.w)};
    return *(const bf16x8*)tmp;
}

// B-operand image: element (k,n) at (((k>>5)*128+n)*4 + (((k>>3)&3)^((n>>1)&3)))*8 + (k&7)
DI int imgIdx(int k, int n) {
    return (((k >> 5) * 128 + n) * 4 + (((k >> 3) & 3) ^ ((n >> 1) & 3))) * 8 + (k & 7);
}
// B fragment (16B) direct from a weight/edge image in global memory.
DI bf16x8 wfragG(const u16* __restrict__ img, int kc, int tt, int l15, int quad) {
    return *(const bf16x8*)&img[(((kc * 128 + tt * 16 + l15) * 4) + (quad ^ ((l15 >> 1) & 3))) * 8];
}

#define MFMA16(a, b, c) __builtin_amdgcn_mfma_f32_16x16x32_bf16(a, b, c, 0, 0, 0)

// ---------------------------------------------------------------- prep 1
__global__ __launch_bounds__(256) void k_prep1(
    const float* __restrict__ linkW, const float* __restrict__ resetW,
    const float* __restrict__ updateW, const float* __restrict__ transW,
    const float* __restrict__ attW1, const float* __restrict__ outW,
    float* __restrict__ W2, u16* __restrict__ linkImg, u16* __restrict__ WrImg,
    u16* __restrict__ WzImg, u16* __restrict__ WhImg, u16* __restrict__ attW1Img,
    u16* __restrict__ outWImg)
{
    int blk = blockIdx.x, t = threadIdx.x;
    if (blk < 256) {
        int idx = blk * 256 + t;
        int out = idx >> 2, q = idx & 3;
        int r = out >> 7, c = out & 127;
        const float* ar = linkW + r * 128 + q * 32;
        float acc = 0.f;
#pragma unroll
        for (int k = 0; k < 32; k++) acc += ar[k] * linkW[(q * 32 + k) * 128 + c];
        acc += __shfl_xor(acc, 1);
        acc += __shfl_xor(acc, 2);
        if (q == 0) W2[out] = acc;
    } else {
        const float* src; u16* dst; int base;
        if (blk < 260)      { src = resetW;  dst = WrImg;    base = 256; }
        else if (blk < 264) { src = updateW; dst = WzImg;    base = 260; }
        else if (blk < 268) { src = transW;  dst = WhImg;    base = 264; }
        else if (blk < 270) { src = linkW;   dst = linkImg;  base = 268; }
        else if (blk < 272) { src = attW1;   dst = attW1Img; base = 270; }
        else                { src = outW;    dst = outWImg;  base = 272; }
        int off = (blk - base) * 8192;
        for (int i = 0; i < 32; i++) {
            int e = off + t + i * 256;
            int k = e >> 7, n = e & 127;
            dst[imgIdx(k, n)] = f2bf(src[e]);
        }
    }
}

// ---------------------------------------------------------------- prep 2
__global__ __launch_bounds__(256) void k_prep2(
    const float* __restrict__ linkW, const float* __restrict__ linkb,
    const float* __restrict__ W2, u16* __restrict__ W3Img, float* __restrict__ ebias)
{
    int blk = blockIdx.x, t = threadIdx.x;
    if (blk < 256) {
        int idx = blk * 256 + t;
        int out = idx >> 2, q = idx & 3;
        int r = out >> 7, c = out & 127;
        const float* ar = W2 + r * 128 + q * 32;
        float acc = 0.f;
#pragma unroll
        for (int k = 0; k < 32; k++) acc += ar[k] * linkW[(q * 32 + k) * 128 + c];
        acc += __shfl_xor(acc, 1);
        acc += __shfl_xor(acc, 2);
        if (q == 0) W3Img[imgIdx(r, c)] = f2bf(acc);
    } else if (t < 128) {
        float acc = linkb[t];
#pragma unroll 8
        for (int k = 0; k < 128; k++) acc += linkb[k] * (W2[k * 128 + t] + linkW[k * 128 + t]);
        ebias[t] = acc;
    }
}

// ---------------------------------------------------------------- E transpose (+edge resid)
__global__ __launch_bounds__(256) void k_te(
    const float* __restrict__ E0, u16* __restrict__ Eswz, float* __restrict__ resid)
{
    __shared__ alignas(16) u16 sT[4096];
    __shared__ float sCol[128];
    int t = threadIdx.x, kc = blockIdx.x, b = blockIdx.y;
    const float* Eb = E0 + (size_t)b * 262144 + (size_t)kc * 32 * 128;
    if (t < 128) sCol[t] = 0.f;
    float part[4] = {0.f, 0.f, 0.f, 0.f};
    int ncol = (t & 31) * 4;
    for (int i = 0; i < 4; i++) {
        int f4i = t + i * 256;
        int k5 = f4i >> 5;
        float4 v = *(const float4*)&Eb[k5 * 128 + ncol];
        int g = k5 >> 3, o = k5 & 7;
        float vv[4] = {v.x, v.y, v.z, v.w};
#pragma unroll
        for (int j = 0; j < 4; j++) {
            int n = ncol + j;
            sT[(n * 4 + (g ^ ((n >> 1) & 3))) * 8 + o] = f2bf(vv[j]);
            part[j] += vv[j];
        }
    }
    __syncthreads();
#pragma unroll
    for (int j = 0; j < 4; j++) atomicAdd(&sCol[ncol + j], part[j]);
    u16* dst = Eswz + (size_t)b * 262144 + (size_t)kc * 4096;
    ((uint4*)dst)[t] = ((const uint4*)sT)[t];
    ((uint4*)dst)[t + 256] = ((const uint4*)sT)[t + 256];
    __syncthreads();
    if (t < 128) atomicAdd(&resid[b * 128 + t], sCol[t]);
}

// ---------------------------------------------------------------- FUSED: G0 = A@E0, then
// all 3 GRU steps + attention. G0 wave split: wave wid -> tt-group tg=wid>>1
// (cols tg*64..+63), K-half kh=wid&1. Pairwise reduction through 8.3KB LDS;
// step-loop operands live in sBuf (rows 0-15 a | 16-31 p | 32-47 r*p) and
// are ds_read inside #pragma-unroll-2 loops.
__global__ __launch_bounds__(256, 4) void k_main(
    const float* __restrict__ A, const u16* __restrict__ Eswz,
    const float* __restrict__ p0,
    const u16* __restrict__ linkImg, const u16* __restrict__ WrImg,
    const u16* __restrict__ WzImg, const u16* __restrict__ WhImg,
    const u16* __restrict__ attW1Img, const u16* __restrict__ outWImg,
    const float* __restrict__ link_b, const float* __restrict__ reset_b,
    const float* __restrict__ update_b, const float* __restrict__ trans_b,
    const float* __restrict__ att_b1, const float* __restrict__ att_W2,
    const float* __restrict__ att_b2, const float* __restrict__ out_b,
    float* __restrict__ atten, float* __restrict__ outPool,
    float* __restrict__ resid)
{
    __shared__ float sAcc2[2][16 * 65];                // 8.3 KB (K-half-1 partials, +1 pad)
    __shared__ float sRs[2][16];
    __shared__ alignas(16) u16 sBuf[48 * 136];         // 12.75 KB operand buffer
    __shared__ float sRed[16];

    int t = threadIdx.x, wid = t >> 6, lane = t & 63, l15 = lane & 15, quad = lane >> 4;
    int tg = wid >> 1, kh = wid & 1;                   // tt-group / K-half
    int bx = blockIdx.x;
    int g = bx >> 8, rmod = bx & 255;
    int b = (rmod & 7) + 8 * g;                        // XCD-affine batch mapping
    int s = (rmod >> 3) & 31;
    size_t r0 = (size_t)b * 512 + (size_t)s * 16;

    // ================= phase G0: acc = A[16 rows] @ E0 (2x2 tt-group x K-half)
    {
        const u16* Eb = Eswz + (size_t)b * 262144;
        const float* Ar = A + (r0 + l15) * 2048 + kh * 1024;

        f32x4 acc[4];
#pragma unroll
        for (int i = 0; i < 4; i++) acc[i] = (f32x4){0.f, 0.f, 0.f, 0.f};
        float rsum = 0.f;

        float4 xc = *(const float4*)&Ar[quad * 8];
        float4 yc = *(const float4*)&Ar[quad * 8 + 4];
        bf16x8 bc[4];
#pragma unroll
        for (int tt = 0; tt < 4; tt++) bc[tt] = wfragG(Eb, kh * 32, tg * 4 + tt, l15, quad);

        for (int kc = 0; kc < 32; kc++) {
            int kg = kh * 32 + kc;
            float4 xn, yn; bf16x8 bn[4];
            if (kc < 31) {
                xn = *(const float4*)&Ar[(kc + 1) * 32 + quad * 8];
                yn = *(const float4*)&Ar[(kc + 1) * 32 + quad * 8 + 4];
#pragma unroll
                for (int tt = 0; tt < 4; tt++) bn[tt] = wfragG(Eb, kg + 1, tg * 4 + tt, l15, quad);
            }
            rsum += xc.x + xc.y + xc.z + xc.w + yc.x + yc.y + yc.z + yc.w;
            bf16x8 af = cvt8(xc, yc);
#pragma unroll
            for (int tt = 0; tt < 4; tt++) acc[tt] = MFMA16(af, bc[tt], acc[tt]);
            if (kc < 31) {
                xc = xn; yc = yn;
#pragma unroll
                for (int tt = 0; tt < 4; tt++) bc[tt] = bn[tt];
            }
        }
        rsum += __shfl_xor(rsum, 16);
        rsum += __shfl_xor(rsum, 32);
        if (quad == 0 && tg == 0) sRs[kh][l15] = rsum;   // per-K-half rowsum
        if (kh == 1) {                                   // dump K-half-1 partials
#pragma unroll
            for (int tt = 0; tt < 4; tt++)
#pragma unroll
                for (int r = 0; r < 4; r++)
                    sAcc2[tg][(quad * 4 + r) * 65 + tt * 16 + l15] = acc[tt][r];
        }
        if (t < 16) sRed[t] = 0.f;                       // attention accumulator
        __syncthreads();
        if (kh == 0) {
            // combine halves in-register, emit bf16 G0 into sBuf rows 0-15
#pragma unroll
            for (int tt = 0; tt < 4; tt++)
#pragma unroll
                for (int r = 0; r < 4; r++) {
                    float v = acc[tt][r] + sAcc2[tg][(quad * 4 + r) * 65 + tt * 16 + l15];
                    sBuf[(quad * 4 + r) * 136 + tg * 64 + tt * 16 + l15] = f2bf(v);
                }
        } else {
            // K-half-1 waves (128 threads) stage p0 -> sBuf rows 16-31
            int idx = tg * 64 + lane;                    // 0..127
            int row = idx >> 3, c8 = (idx & 7) * 16;
            const float* pr = &p0[(r0 + row) * 128 + c8];
            float4 x0 = *(const float4*)&pr[0];
            float4 y0 = *(const float4*)&pr[4];
            float4 x1 = *(const float4*)&pr[8];
            float4 y1 = *(const float4*)&pr[12];
            *(bf16x8*)&sBuf[(16 + row) * 136 + c8] = cvt8(x0, y0);
            *(bf16x8*)&sBuf[(16 + row) * 136 + c8 + 8] = cvt8(x1, y1);
        }
    }
    __syncthreads();

    // ================= phase steps: 3 GRU steps + attention (row-local)
    int ttA = wid * 2, ttB = wid * 2 + 1;              // this wave's column tiles
    int colA = ttA * 16 + l15, colB = ttB * 16 + l15;

    // own-col fp32 p state (C layout: rows quad*4+r)
    f32x4 pS[2];
#pragma unroll
    for (int j = 0; j < 2; j++)
#pragma unroll
        for (int r = 0; r < 4; r++)
            pS[j][r] = p0[(r0 + quad * 4 + r) * 128 + (wid * 2 + j) * 16 + l15];
    // node part of the residual: sum over this block's 16 rows, own cols
    {
        float s0 = pS[0][0] + pS[0][1] + pS[0][2] + pS[0][3];
        float s1 = pS[1][0] + pS[1][1] + pS[1][2] + pS[1][3];
        s0 += __shfl_xor(s0, 16); s0 += __shfl_xor(s0, 32);
        s1 += __shfl_xor(s1, 16); s1 += __shfl_xor(s1, 32);
        if (quad == 0) {
            atomicAdd(&resid[b * 128 + colA], s0);
            atomicAdd(&resid[b * 128 + colB], s1);
        }
    }
    float sv[4];
#pragma unroll
    for (int r = 0; r < 4; r++) sv[r] = sRs[0][quad * 4 + r] + sRs[1][quad * 4 + r];
    float lbA = link_b[colA], lbB = link_b[colB];
    float rbA = reset_b[colA], rbB = reset_b[colB];
    float ubA = update_b[colA], ubB = update_b[colB];
    float tbA = trans_b[colA], tbB = trans_b[colB];

    f32x4 zero4 = {0.f, 0.f, 0.f, 0.f};
    int fcol = quad * 8;             // fragment col base (u16 units)
    for (int step = 0; step < 3; step++) {
        // ---- phase 1: a_new (own cols) = a @ linkW + rowsum*link_b
        f32x4 cA = zero4, cB = zero4;
#pragma unroll 2
        for (int kc = 0; kc < 4; kc++) {
            bf16x8 af = *(const bf16x8*)&sBuf[l15 * 136 + kc * 32 + fcol];
            cA = MFMA16(af, wfragG(linkImg, kc, ttA, l15, quad), cA);
            cB = MFMA16(af, wfragG(linkImg, kc, ttB, l15, quad), cB);
        }
        __syncthreads();             // all reads of rows 0-15 done before rewrite
#pragma unroll
        for (int r = 0; r < 4; r++) {
            sBuf[(quad * 4 + r) * 136 + colA] = f2bf(cA[r] + sv[r] * lbA);
            sBuf[(quad * 4 + r) * 136 + colB] = f2bf(cB[r] + sv[r] * lbB);
        }
        __syncthreads();             // a_new visible
        // ---- phase 2: r, z (own cols), K=256 over [a_new(rows 0-15), p(rows 16-31)]
        f32x4 rA = zero4, rB = zero4, zA = zero4, zB = zero4;
#pragma unroll 2
        for (int kc = 0; kc < 8; kc++) {
            int row = ((kc >> 2) * 16 + l15) * 136 + (kc & 3) * 32 + fcol;
            bf16x8 af = *(const bf16x8*)&sBuf[row];
            rA = MFMA16(af, wfragG(WrImg, kc, ttA, l15, quad), rA);
            rB = MFMA16(af, wfragG(WrImg, kc, ttB, l15, quad), rB);
            zA = MFMA16(af, wfragG(WzImg, kc, ttA, l15, quad), zA);
            zB = MFMA16(af, wfragG(WzImg, kc, ttB, l15, quad), zB);
        }
#pragma unroll
        for (int r = 0; r < 4; r++) {
            float rvA = 1.f / (1.f + __expf(-(rA[r] + rbA)));
            float rvB = 1.f / (1.f + __expf(-(rB[r] + rbB)));
            zA[r] = 1.f / (1.f + __expf(-(zA[r] + ubA)));
            zB[r] = 1.f / (1.f + __expf(-(zB[r] + ubB)));
            sBuf[(32 + quad * 4 + r) * 136 + colA] = f2bf(rvA * pS[0][r]);
            sBuf[(32 + quad * 4 + r) * 136 + colB] = f2bf(rvB * pS[1][r]);
        }
        __syncthreads();             // r*p (rows 32-47) visible
        // ---- phase 3: h (own cols), K=256 over [a_new(rows 0-15), r*p(rows 32-47)]
        f32x4 hA = zero4, hB = zero4;
#pragma unroll 2
        for (int kc = 0; kc < 8; kc++) {
            int row = ((kc >> 2) * 32 + l15) * 136 + (kc & 3) * 32 + fcol;
            bf16x8 af = *(const bf16x8*)&sBuf[row];
            hA = MFMA16(af, wfragG(WhImg, kc, ttA, l15, quad), hA);
            hB = MFMA16(af, wfragG(WhImg, kc, ttB, l15, quad), hB);
        }
#pragma unroll
        for (int r = 0; r < 4; r++) {
            float h1 = tanhf(hA[r] + tbA), h2 = tanhf(hB[r] + tbB);
            pS[0][r] = (1.f - zA[r]) * pS[0][r] + zA[r] * h1;
            pS[1][r] = (1.f - zB[r]) * pS[1][r] + zB[r] * h2;
            sBuf[(16 + quad * 4 + r) * 136 + colA] = f2bf(pS[0][r]);
            sBuf[(16 + quad * 4 + r) * 136 + colB] = f2bf(pS[1][r]);
        }
        __syncthreads();             // p (rows 16-31) visible for next step / attention
    }
    // ---- attention + out (own cols), A-operand = p3 (rows 16-31)
    f32x4 atA = zero4, atB = zero4, oA = zero4, oB = zero4;
#pragma unroll 2
    for (int kc = 0; kc < 4; kc++) {
        bf16x8 pf = *(const bf16x8*)&sBuf[(16 + l15) * 136 + kc * 32 + fcol];
        atA = MFMA16(pf, wfragG(attW1Img, kc, ttA, l15, quad), atA);
        atB = MFMA16(pf, wfragG(attW1Img, kc, ttB, l15, quad), atB);
        oA  = MFMA16(pf, wfragG(outWImg,  kc, ttA, l15, quad), oA);
        oB  = MFMA16(pf, wfragG(outWImg,  kc, ttB, l15, quad), oB);
    }
    float b1A = att_b1[colA], b1B = att_b1[colB];
    float w2A = att_W2[colA], w2B = att_W2[colB];
    float obA = out_b[colA],  obB = out_b[colB];
    float pr[4];
#pragma unroll
    for (int r = 0; r < 4; r++) {
        pr[r] = tanhf(atA[r] + b1A) * w2A + tanhf(atB[r] + b1B) * w2B;
        outPool[(r0 + quad * 4 + r) * 128 + colA] = tanhf(oA[r] + obA);
        outPool[(r0 + quad * 4 + r) * 128 + colB] = tanhf(oB[r] + obB);
    }
#pragma unroll
    for (int r = 0; r < 4; r++) {
        float v = pr[r];
        v += __shfl_xor(v, 1); v += __shfl_xor(v, 2);
        v += __shfl_xor(v, 4); v += __shfl_xor(v, 8);
        if (l15 == 0) atomicAdd(&sRed[quad * 4 + r], v);
    }
    __syncthreads();
    if (t < 16) atten[r0 + t] = sRed[t] + att_b2[0];
}

// ---------------------------------------------------------------- edges out: E0@W3 + ebias
__global__ __launch_bounds__(64) void k_eout(
    const float* __restrict__ E0, const u16* __restrict__ W3Img,
    const float* __restrict__ ebias, float* __restrict__ Eout)
{
    int t = threadIdx.x, l15 = t & 15, quad = t >> 4;
    size_t r0 = (size_t)blockIdx.x * 16;
    bf16x8 eF[4];
#pragma unroll
    for (int kc = 0; kc < 4; kc++) {
        float4 x = *(const float4*)&E0[(r0 + l15) * 128 + kc * 32 + quad * 8];
        float4 y = *(const float4*)&E0[(r0 + l15) * 128 + kc * 32 + quad * 8 + 4];
        eF[kc] = cvt8(x, y);
    }
    f32x4 acc[8];
#pragma unroll
    for (int i = 0; i < 8; i++) acc[i] = (f32x4){0.f, 0.f, 0.f, 0.f};
    {
        bf16x8 wc[8], wn[8];
#pragma unroll
        for (int tt = 0; tt < 8; tt++) wc[tt] = wfragG(W3Img, 0, tt, l15, quad);
#pragma unroll
        for (int kc = 0; kc < 4; kc++) {
            if (kc < 3)
#pragma unroll
                for (int tt = 0; tt < 8; tt++) wn[tt] = wfragG(W3Img, kc + 1, tt, l15, quad);
#pragma unroll
            for (int tt = 0; tt < 8; tt++) acc[tt] = MFMA16(eF[kc], wc[tt], acc[tt]);
            if (kc < 3)
#pragma unroll
                for (int tt = 0; tt < 8; tt++) wc[tt] = wn[tt];
        }
    }
#pragma unroll
    for (int tt = 0; tt < 8; tt++) {
        int col = tt * 16 + l15; float eb = ebias[col];
#pragma unroll
        for (int r = 0; r < 4; r++)
            Eout[(r0 + quad * 4 + r) * 128 + col] = acc[tt][r] + eb;
    }
}

// ---------------------------------------------------------------- softmax-pool + residual
__global__ __launch_bounds__(512) void k_fin(
    const float* __restrict__ atten, const float* __restrict__ outPool,
    const float* __restrict__ resid,
    float* __restrict__ outRes, float* __restrict__ outMul)
{
    __shared__ float swv[512];
    __shared__ float sred[512];
    __shared__ float sacc[4][128];
    int t = threadIdx.x, b = blockIdx.x;
    float a = atten[b * 512 + t];
    sred[t] = a; __syncthreads();
    for (int s = 256; s > 0; s >>= 1) { if (t < s) sred[t] = fmaxf(sred[t], sred[t + s]); __syncthreads(); }
    float mx = sred[0]; __syncthreads();
    float e = __expf(a - mx);
    swv[t] = e; sred[t] = e; __syncthreads();
    for (int s = 256; s > 0; s >>= 1) { if (t < s) sred[t] += sred[t + s]; __syncthreads(); }
    float Z = sred[0]; __syncthreads();
    int col = t & 127, q = t >> 7;
    const float* op = outPool + ((size_t)b * 512 + q * 128) * 128 + col;
    float accM = 0.f;
#pragma unroll 8
    for (int n = 0; n < 128; n++) accM += swv[q * 128 + n] * op[(size_t)n * 128];
    sacc[q][col] = accM;
    __syncthreads();
    if (t < 128) {
        float mulv = (sacc[0][t] + sacc[1][t] + sacc[2][t] + sacc[3][t]) / Z;
        float rv = resid[b * 128 + t] * (1.f / 2560.f);
        outMul[b * 128 + t] = mulv;
        outRes[b * 128 + t] = fmaxf(0.f, tanhf(mulv) + rv);
    }
}

// ================================================================ launch
extern "C" void kernel_launch(void* const* d_in, const int* in_sizes, int n_in,
                              void* d_out, int out_size, void* d_ws, size_t ws_size,
                              hipStream_t stream)
{
    const float* prop0  = (const float*)d_in[0];
    const float* edge0  = (const float*)d_in[1];
    const float* Amat   = (const float*)d_in[2];
    const float* linkW  = (const float*)d_in[4];
    const float* linkb  = (const float*)d_in[5];
    const float* resetW = (const float*)d_in[6];
    const float* resetb = (const float*)d_in[7];
    const float* updateW= (const float*)d_in[8];
    const float* updateb= (const float*)d_in[9];
    const float* transW = (const float*)d_in[10];
    const float* transb = (const float*)d_in[11];
    const float* attW1  = (const float*)d_in[12];
    const float* attb1  = (const float*)d_in[13];
    const float* attW2  = (const float*)d_in[14];
    const float* attb2  = (const float*)d_in[15];
    const float* outW   = (const float*)d_in[16];
    const float* outb   = (const float*)d_in[17];

    char* w = (char*)d_ws;
    float* ws_atten   = (float*)(w + 4259840);        //    65,536 B
    float* ws_resid   = (float*)(w + 4325376);        //    16,384 B
    float* ws_W2      = (float*)(w + 4341760);        //    65,536 B
    float* ws_ebias   = (float*)(w + 4407296);        //       512 B
    u16*   ws_linkImg = (u16*)(w + 4407808);          //    32,768 B
    u16*   ws_W3Img   = (u16*)(w + 4440576);          //    32,768 B
    u16*   ws_WrImg   = (u16*)(w + 4473344);          //    65,536 B
    u16*   ws_WzImg   = (u16*)(w + 4538880);          //    65,536 B
    u16*   ws_WhImg   = (u16*)(w + 4604416);          //    65,536 B
    u16*   ws_attW1Img= (u16*)(w + 4669952);          //    32,768 B
    u16*   ws_outWImg = (u16*)(w + 4702720);          //    32,768 B (~4.7 MB)

    float* out_res  = (float*)d_out;
    float* out_mul  = out_res + 4096;
    float* out_edge = out_res + 8192;
    // Scratch inside d_out edge region (dead until k_eout, which runs last):
    u16*   Eswz     = (u16*)out_edge;                 // 16.78 MB
    float* outPool  = out_edge + 4194304;             // next 8.39 MB

    hipMemsetAsync(ws_resid, 0, 32 * 128 * sizeof(float), stream);
    k_prep1<<<274, 256, 0, stream>>>(linkW, resetW, updateW, transW, attW1, outW,
                                     ws_W2, ws_linkImg, ws_WrImg, ws_WzImg, ws_WhImg,
                                     ws_attW1Img, ws_outWImg);
    k_prep2<<<257, 256, 0, stream>>>(linkW, linkb, ws_W2, ws_W3Img, ws_ebias);
    k_te<<<dim3(64, 32), 256, 0, stream>>>(edge0, Eswz, ws_resid);
    k_main<<<1024, 256, 0, stream>>>(Amat, Eswz, prop0,
                                     ws_linkImg, ws_WrImg, ws_WzImg, ws_WhImg,
                                     ws_attW1Img, ws_outWImg,
                                     linkb, resetb, updateb, transb,
                                     attb1, attW2, attb2, outb,
                                     ws_atten, outPool, ws_resid);
    k_fin<<<32, 512, 0, stream>>>(ws_atten, outPool, ws_resid, out_res, out_mul);
    k_eout<<<4096, 64, 0, stream>>>(edge0, ws_W3Img, ws_ebias, out_edge);
}

// Round 5
// 350.519 us; speedup vs baseline: 1.3971x; 1.0540x over previous
//
#include <hip/hip_runtime.h>
#include <hip/hip_bf16.h>

// SpatialRelation on MI355X — round 9.
// R7/R8 evidence: k_main time invariant to occupancy (2 vs 4 blocks/CU both
// ~123us) => a shared resource is saturated, not latency/occupancy. Traffic
// audit: weights re-read per wave per step ~820MB, Eswz re-read 32x/batch
// 512MB, A 268MB — ~1.6GB of L2-served requests at 16 lines/instr ~= L2
// request-rate ceiling. R9: M=32 rows/block (grid 512): every B/weight
// fragment load now feeds TWO row-groups of MFMAs => weights 820->410MB,
// Eswz 512->256MB. launch_bounds(256,2) (2 blocks/CU resident anyway) =>
// 256-reg cap, no spill risk; unroll 4 on 8-kc loops. k_eout gets the same
// M=32 treatment; k_fin widened to 1024 threads.

typedef unsigned short u16;
typedef __attribute__((ext_vector_type(4))) float f32x4;
typedef __attribute__((ext_vector_type(8))) short bf16x8;

#define DI static __device__ __forceinline__

DI u16 f2bf(float f) {
    unsigned u = __builtin_bit_cast(unsigned, f);
    return (u16)((u + 0x7fffu + ((u >> 16) & 1u)) >> 16);  // RNE
}

DI bf16x8 cvt8(float4 a, float4 b) {
    u16 tmp[8] = {f2bf(a.x), f2bf(a.y), f2bf(a.z), f2bf(a.w),
                  f2bf(b.x), f2bf(b.y), f2bf(b.z), f2bf(b.w)};
    return *(const bf16x8*)tmp;
}

// B-operand image: element (k,n) at (((k>>5)*128+n)*4 + (((k>>3)&3)^((n>>1)&3)))*8 + (k&7)
DI int imgIdx(int k, int n) {
    return (((k >> 5) * 128 + n) * 4 + (((k >> 3) & 3) ^ ((n >> 1) & 3))) * 8 + (k & 7);
}
// B fragment (16B) direct from a weight/edge image in global memory.
DI bf16x8 wfragG(const u16* __restrict__ img, int kc, int tt, int l15, int quad) {
    return *(const bf16x8*)&img[(((kc * 128 + tt * 16 + l15) * 4) + (quad ^ ((l15 >> 1) & 3))) * 8];
}

#define MFMA16(a, b, c) __builtin_amdgcn_mfma_f32_16x16x32_bf16(a, b, c, 0, 0, 0)

// ---------------------------------------------------------------- prep 1
__global__ __launch_bounds__(256) void k_prep1(
    const float* __restrict__ linkW, const float* __restrict__ resetW,
    const float* __restrict__ updateW, const float* __restrict__ transW,
    const float* __restrict__ attW1, const float* __restrict__ outW,
    float* __restrict__ W2, u16* __restrict__ linkImg, u16* __restrict__ WrImg,
    u16* __restrict__ WzImg, u16* __restrict__ WhImg, u16* __restrict__ attW1Img,
    u16* __restrict__ outWImg)
{
    int blk = blockIdx.x, t = threadIdx.x;
    if (blk < 256) {
        int idx = blk * 256 + t;
        int out = idx >> 2, q = idx & 3;
        int r = out >> 7, c = out & 127;
        const float* ar = linkW + r * 128 + q * 32;
        float acc = 0.f;
#pragma unroll
        for (int k = 0; k < 32; k++) acc += ar[k] * linkW[(q * 32 + k) * 128 + c];
        acc += __shfl_xor(acc, 1);
        acc += __shfl_xor(acc, 2);
        if (q == 0) W2[out] = acc;
    } else {
        const float* src; u16* dst; int base;
        if (blk < 260)      { src = resetW;  dst = WrImg;    base = 256; }
        else if (blk < 264) { src = updateW; dst = WzImg;    base = 260; }
        else if (blk < 268) { src = transW;  dst = WhImg;    base = 264; }
        else if (blk < 270) { src = linkW;   dst = linkImg;  base = 268; }
        else if (blk < 272) { src = attW1;   dst = attW1Img; base = 270; }
        else                { src = outW;    dst = outWImg;  base = 272; }
        int off = (blk - base) * 8192;
        for (int i = 0; i < 32; i++) {
            int e = off + t + i * 256;
            int k = e >> 7, n = e & 127;
            dst[imgIdx(k, n)] = f2bf(src[e]);
        }
    }
}

// ---------------------------------------------------------------- prep 2
__global__ __launch_bounds__(256) void k_prep2(
    const float* __restrict__ linkW, const float* __restrict__ linkb,
    const float* __restrict__ W2, u16* __restrict__ W3Img, float* __restrict__ ebias)
{
    int blk = blockIdx.x, t = threadIdx.x;
    if (blk < 256) {
        int idx = blk * 256 + t;
        int out = idx >> 2, q = idx & 3;
        int r = out >> 7, c = out & 127;
        const float* ar = W2 + r * 128 + q * 32;
        float acc = 0.f;
#pragma unroll
        for (int k = 0; k < 32; k++) acc += ar[k] * linkW[(q * 32 + k) * 128 + c];
        acc += __shfl_xor(acc, 1);
        acc += __shfl_xor(acc, 2);
        if (q == 0) W3Img[imgIdx(r, c)] = f2bf(acc);
    } else if (t < 128) {
        float acc = linkb[t];
#pragma unroll 8
        for (int k = 0; k < 128; k++) acc += linkb[k] * (W2[k * 128 + t] + linkW[k * 128 + t]);
        ebias[t] = acc;
    }
}

// ---------------------------------------------------------------- E transpose (+edge resid)
__global__ __launch_bounds__(256) void k_te(
    const float* __restrict__ E0, u16* __restrict__ Eswz, float* __restrict__ resid)
{
    __shared__ alignas(16) u16 sT[4096];
    __shared__ float sCol[128];
    int t = threadIdx.x, kc = blockIdx.x, b = blockIdx.y;
    const float* Eb = E0 + (size_t)b * 262144 + (size_t)kc * 32 * 128;
    if (t < 128) sCol[t] = 0.f;
    float part[4] = {0.f, 0.f, 0.f, 0.f};
    int ncol = (t & 31) * 4;
    for (int i = 0; i < 4; i++) {
        int f4i = t + i * 256;
        int k5 = f4i >> 5;
        float4 v = *(const float4*)&Eb[k5 * 128 + ncol];
        int g = k5 >> 3, o = k5 & 7;
        float vv[4] = {v.x, v.y, v.z, v.w};
#pragma unroll
        for (int j = 0; j < 4; j++) {
            int n = ncol + j;
            sT[(n * 4 + (g ^ ((n >> 1) & 3))) * 8 + o] = f2bf(vv[j]);
            part[j] += vv[j];
        }
    }
    __syncthreads();
#pragma unroll
    for (int j = 0; j < 4; j++) atomicAdd(&sCol[ncol + j], part[j]);
    u16* dst = Eswz + (size_t)b * 262144 + (size_t)kc * 4096;
    ((uint4*)dst)[t] = ((const uint4*)sT)[t];
    ((uint4*)dst)[t + 256] = ((const uint4*)sT)[t + 256];
    __syncthreads();
    if (t < 128) atomicAdd(&resid[b * 128 + t], sCol[t]);
}

// ---------------------------------------------------------------- FUSED: G0 = A@E0 (32 rows),
// then 3 GRU steps + attention for both 16-row groups. Wave (tg,kh) in G0;
// wave = tt-pair in steps, iterating rg 0/1 so each weight fragment feeds
// 2x MFMAs. sBuf rows: 0-31 a | 32-63 p | 64-95 r*p.
__global__ __launch_bounds__(256, 2) void k_main(
    const float* __restrict__ A, const u16* __restrict__ Eswz,
    const float* __restrict__ p0,
    const u16* __restrict__ linkImg, const u16* __restrict__ WrImg,
    const u16* __restrict__ WzImg, const u16* __restrict__ WhImg,
    const u16* __restrict__ attW1Img, const u16* __restrict__ outWImg,
    const float* __restrict__ link_b, const float* __restrict__ reset_b,
    const float* __restrict__ update_b, const float* __restrict__ trans_b,
    const float* __restrict__ att_b1, const float* __restrict__ att_W2,
    const float* __restrict__ att_b2, const float* __restrict__ out_b,
    float* __restrict__ atten, float* __restrict__ outPool,
    float* __restrict__ resid)
{
    __shared__ float sAcc2[2][2][16 * 65];             // 16.6 KB: [tg][rg] K-half-1 partials
    __shared__ float sRs[2][32];                       // [kh][row] rowsum partials
    __shared__ alignas(16) u16 sBuf[96 * 136];         // 26.1 KB operand buffer
    __shared__ float sRed[32];

    int t = threadIdx.x, wid = t >> 6, lane = t & 63, l15 = lane & 15, quad = lane >> 4;
    int tg = wid >> 1, kh = wid & 1;                   // G0: tt-group / K-half
    int bx = blockIdx.x;
    int g = bx >> 7, rmod = bx & 127;
    int b = (rmod & 7) + 8 * g;                        // XCD-affine batch mapping
    int s = (rmod >> 3) & 15;
    size_t r0 = (size_t)b * 512 + (size_t)s * 32;

    // ================= phase G0: acc = A[32 rows] @ E0; B frags reused for both row-groups
    {
        const u16* Eb = Eswz + (size_t)b * 262144;
        const float* Ar0 = A + (r0 + l15) * 2048 + kh * 1024;
        const float* Ar1 = A + (r0 + 16 + l15) * 2048 + kh * 1024;

        f32x4 acc[2][4];
#pragma unroll
        for (int rg = 0; rg < 2; rg++)
#pragma unroll
            for (int i = 0; i < 4; i++) acc[rg][i] = (f32x4){0.f, 0.f, 0.f, 0.f};
        float rs0 = 0.f, rs1 = 0.f;

        float4 x0 = *(const float4*)&Ar0[quad * 8];
        float4 y0 = *(const float4*)&Ar0[quad * 8 + 4];
        float4 x1 = *(const float4*)&Ar1[quad * 8];
        float4 y1 = *(const float4*)&Ar1[quad * 8 + 4];
        rs0 += x0.x + x0.y + x0.z + x0.w + y0.x + y0.y + y0.z + y0.w;
        rs1 += x1.x + x1.y + x1.z + x1.w + y1.x + y1.y + y1.z + y1.w;
        bf16x8 aF0 = cvt8(x0, y0), aF1 = cvt8(x1, y1);
        bf16x8 bc[4];
#pragma unroll
        for (int tt = 0; tt < 4; tt++) bc[tt] = wfragG(Eb, kh * 32, tg * 4 + tt, l15, quad);

        for (int kc = 0; kc < 32; kc++) {
            float4 xn0, yn0, xn1, yn1; bf16x8 bn[4];
            if (kc < 31) {
                xn0 = *(const float4*)&Ar0[(kc + 1) * 32 + quad * 8];
                yn0 = *(const float4*)&Ar0[(kc + 1) * 32 + quad * 8 + 4];
                xn1 = *(const float4*)&Ar1[(kc + 1) * 32 + quad * 8];
                yn1 = *(const float4*)&Ar1[(kc + 1) * 32 + quad * 8 + 4];
#pragma unroll
                for (int tt = 0; tt < 4; tt++)
                    bn[tt] = wfragG(Eb, kh * 32 + kc + 1, tg * 4 + tt, l15, quad);
            }
#pragma unroll
            for (int tt = 0; tt < 4; tt++) {
                acc[0][tt] = MFMA16(aF0, bc[tt], acc[0][tt]);
                acc[1][tt] = MFMA16(aF1, bc[tt], acc[1][tt]);
            }
            if (kc < 31) {
                rs0 += xn0.x + xn0.y + xn0.z + xn0.w + yn0.x + yn0.y + yn0.z + yn0.w;
                rs1 += xn1.x + xn1.y + xn1.z + xn1.w + yn1.x + yn1.y + yn1.z + yn1.w;
                aF0 = cvt8(xn0, yn0); aF1 = cvt8(xn1, yn1);
#pragma unroll
                for (int tt = 0; tt < 4; tt++) bc[tt] = bn[tt];
            }
        }
        rs0 += __shfl_xor(rs0, 16); rs0 += __shfl_xor(rs0, 32);
        rs1 += __shfl_xor(rs1, 16); rs1 += __shfl_xor(rs1, 32);
        if (quad == 0 && tg == 0) { sRs[kh][l15] = rs0; sRs[kh][16 + l15] = rs1; }
        if (kh == 1) {
#pragma unroll
            for (int rg = 0; rg < 2; rg++)
#pragma unroll
                for (int tt = 0; tt < 4; tt++)
#pragma unroll
                    for (int r = 0; r < 4; r++)
                        sAcc2[tg][rg][(quad * 4 + r) * 65 + tt * 16 + l15] = acc[rg][tt][r];
        }
        if (t < 32) sRed[t] = 0.f;                     // attention accumulator
        __syncthreads();
        if (kh == 0) {
            // combine K-halves, emit bf16 G0 into sBuf rows 0-31
#pragma unroll
            for (int rg = 0; rg < 2; rg++)
#pragma unroll
                for (int tt = 0; tt < 4; tt++)
#pragma unroll
                    for (int r = 0; r < 4; r++) {
                        float v = acc[rg][tt][r] + sAcc2[tg][rg][(quad * 4 + r) * 65 + tt * 16 + l15];
                        sBuf[(rg * 16 + quad * 4 + r) * 136 + tg * 64 + tt * 16 + l15] = f2bf(v);
                    }
        } else {
            // K-half-1 waves (128 threads) stage p0 -> sBuf rows 32-63
            int idx = tg * 64 + lane;                  // 0..127
            int row = idx >> 2, cq = (idx & 3) * 32;
            const float* pr = &p0[(r0 + row) * 128 + cq];
#pragma unroll
            for (int j = 0; j < 4; j++) {
                float4 x = *(const float4*)&pr[j * 8];
                float4 y = *(const float4*)&pr[j * 8 + 4];
                *(bf16x8*)&sBuf[(32 + row) * 136 + cq + j * 8] = cvt8(x, y);
            }
        }
    }
    __syncthreads();

    // ================= steps: 3 GRU steps + attention; wave owns tt-pair, loops rg 0/1
    int ttA = wid * 2, ttB = wid * 2 + 1;
    int colA = ttA * 16 + l15, colB = ttB * 16 + l15;

    // own-col fp32 p state for both row-groups
    f32x4 pS[2][2];
#pragma unroll
    for (int rg = 0; rg < 2; rg++)
#pragma unroll
        for (int j = 0; j < 2; j++)
#pragma unroll
            for (int r = 0; r < 4; r++)
                pS[rg][j][r] = p0[(r0 + rg * 16 + quad * 4 + r) * 128 + (wid * 2 + j) * 16 + l15];
    // node residual: sum over this block's 32 rows, own cols
    {
        float s0 = pS[0][0][0] + pS[0][0][1] + pS[0][0][2] + pS[0][0][3]
                 + pS[1][0][0] + pS[1][0][1] + pS[1][0][2] + pS[1][0][3];
        float s1 = pS[0][1][0] + pS[0][1][1] + pS[0][1][2] + pS[0][1][3]
                 + pS[1][1][0] + pS[1][1][1] + pS[1][1][2] + pS[1][1][3];
        s0 += __shfl_xor(s0, 16); s0 += __shfl_xor(s0, 32);
        s1 += __shfl_xor(s1, 16); s1 += __shfl_xor(s1, 32);
        if (quad == 0) {
            atomicAdd(&resid[b * 128 + colA], s0);
            atomicAdd(&resid[b * 128 + colB], s1);
        }
    }
    float sv[2][4];
#pragma unroll
    for (int rg = 0; rg < 2; rg++)
#pragma unroll
        for (int r = 0; r < 4; r++)
            sv[rg][r] = sRs[0][rg * 16 + quad * 4 + r] + sRs[1][rg * 16 + quad * 4 + r];
    float lbA = link_b[colA], lbB = link_b[colB];
    float rbA = reset_b[colA], rbB = reset_b[colB];
    float ubA = update_b[colA], ubB = update_b[colB];
    float tbA = trans_b[colA], tbB = trans_b[colB];

    f32x4 zero4 = {0.f, 0.f, 0.f, 0.f};
    int fcol = quad * 8;
    for (int step = 0; step < 3; step++) {
        // ---- phase 1: a_new = a @ linkW + rowsum*link_b (weights shared across rgs)
        f32x4 cc[2][2];
#pragma unroll
        for (int rg = 0; rg < 2; rg++) { cc[rg][0] = zero4; cc[rg][1] = zero4; }
#pragma unroll
        for (int kc = 0; kc < 4; kc++) {
            bf16x8 wla = wfragG(linkImg, kc, ttA, l15, quad);
            bf16x8 wlb = wfragG(linkImg, kc, ttB, l15, quad);
            bf16x8 af0 = *(const bf16x8*)&sBuf[l15 * 136 + kc * 32 + fcol];
            bf16x8 af1 = *(const bf16x8*)&sBuf[(16 + l15) * 136 + kc * 32 + fcol];
            cc[0][0] = MFMA16(af0, wla, cc[0][0]); cc[0][1] = MFMA16(af0, wlb, cc[0][1]);
            cc[1][0] = MFMA16(af1, wla, cc[1][0]); cc[1][1] = MFMA16(af1, wlb, cc[1][1]);
        }
        __syncthreads();             // reads of rows 0-31 done before rewrite
#pragma unroll
        for (int rg = 0; rg < 2; rg++)
#pragma unroll
            for (int r = 0; r < 4; r++) {
                sBuf[(rg * 16 + quad * 4 + r) * 136 + colA] = f2bf(cc[rg][0][r] + sv[rg][r] * lbA);
                sBuf[(rg * 16 + quad * 4 + r) * 136 + colB] = f2bf(cc[rg][1][r] + sv[rg][r] * lbB);
            }
        __syncthreads();             // a_new visible
        // ---- phase 2: r, z; K=256 over [a_new(0-31), p(32-63)]
        f32x4 rr[2][2], zz[2][2];
#pragma unroll
        for (int rg = 0; rg < 2; rg++) { rr[rg][0] = zero4; rr[rg][1] = zero4; zz[rg][0] = zero4; zz[rg][1] = zero4; }
#pragma unroll 4
        for (int kc = 0; kc < 8; kc++) {
            int base = (kc >> 2) * 32;
            bf16x8 wra = wfragG(WrImg, kc, ttA, l15, quad);
            bf16x8 wrb = wfragG(WrImg, kc, ttB, l15, quad);
            bf16x8 wza = wfragG(WzImg, kc, ttA, l15, quad);
            bf16x8 wzb = wfragG(WzImg, kc, ttB, l15, quad);
            bf16x8 af0 = *(const bf16x8*)&sBuf[(base + l15) * 136 + (kc & 3) * 32 + fcol];
            bf16x8 af1 = *(const bf16x8*)&sBuf[(base + 16 + l15) * 136 + (kc & 3) * 32 + fcol];
            rr[0][0] = MFMA16(af0, wra, rr[0][0]); rr[0][1] = MFMA16(af0, wrb, rr[0][1]);
            zz[0][0] = MFMA16(af0, wza, zz[0][0]); zz[0][1] = MFMA16(af0, wzb, zz[0][1]);
            rr[1][0] = MFMA16(af1, wra, rr[1][0]); rr[1][1] = MFMA16(af1, wrb, rr[1][1]);
            zz[1][0] = MFMA16(af1, wza, zz[1][0]); zz[1][1] = MFMA16(af1, wzb, zz[1][1]);
        }
#pragma unroll
        for (int rg = 0; rg < 2; rg++)
#pragma unroll
            for (int r = 0; r < 4; r++) {
                float rvA = 1.f / (1.f + __expf(-(rr[rg][0][r] + rbA)));
                float rvB = 1.f / (1.f + __expf(-(rr[rg][1][r] + rbB)));
                zz[rg][0][r] = 1.f / (1.f + __expf(-(zz[rg][0][r] + ubA)));
                zz[rg][1][r] = 1.f / (1.f + __expf(-(zz[rg][1][r] + ubB)));
                sBuf[(64 + rg * 16 + quad * 4 + r) * 136 + colA] = f2bf(rvA * pS[rg][0][r]);
                sBuf[(64 + rg * 16 + quad * 4 + r) * 136 + colB] = f2bf(rvB * pS[rg][1][r]);
            }
        __syncthreads();             // r*p (rows 64-95) visible
        // ---- phase 3: h; K=256 over [a_new(0-31), r*p(64-95)]
        f32x4 hh[2][2];
#pragma unroll
        for (int rg = 0; rg < 2; rg++) { hh[rg][0] = zero4; hh[rg][1] = zero4; }
#pragma unroll 4
        for (int kc = 0; kc < 8; kc++) {
            int base = (kc >> 2) * 64;
            bf16x8 wha = wfragG(WhImg, kc, ttA, l15, quad);
            bf16x8 whb = wfragG(WhImg, kc, ttB, l15, quad);
            bf16x8 af0 = *(const bf16x8*)&sBuf[(base + l15) * 136 + (kc & 3) * 32 + fcol];
            bf16x8 af1 = *(const bf16x8*)&sBuf[(base + 16 + l15) * 136 + (kc & 3) * 32 + fcol];
            hh[0][0] = MFMA16(af0, wha, hh[0][0]); hh[0][1] = MFMA16(af0, whb, hh[0][1]);
            hh[1][0] = MFMA16(af1, wha, hh[1][0]); hh[1][1] = MFMA16(af1, whb, hh[1][1]);
        }
#pragma unroll
        for (int rg = 0; rg < 2; rg++)
#pragma unroll
            for (int r = 0; r < 4; r++) {
                float h1 = tanhf(hh[rg][0][r] + tbA), h2 = tanhf(hh[rg][1][r] + tbB);
                pS[rg][0][r] = (1.f - zz[rg][0][r]) * pS[rg][0][r] + zz[rg][0][r] * h1;
                pS[rg][1][r] = (1.f - zz[rg][1][r]) * pS[rg][1][r] + zz[rg][1][r] * h2;
                sBuf[(32 + rg * 16 + quad * 4 + r) * 136 + colA] = f2bf(pS[rg][0][r]);
                sBuf[(32 + rg * 16 + quad * 4 + r) * 136 + colB] = f2bf(pS[rg][1][r]);
            }
        __syncthreads();             // p (rows 32-63) visible
    }
    // ---- attention + out; A-operand = p3 (rows 32-63), weights shared across rgs
    f32x4 at[2][2], oo[2][2];
#pragma unroll
    for (int rg = 0; rg < 2; rg++) { at[rg][0] = zero4; at[rg][1] = zero4; oo[rg][0] = zero4; oo[rg][1] = zero4; }
#pragma unroll
    for (int kc = 0; kc < 4; kc++) {
        bf16x8 wa  = wfragG(attW1Img, kc, ttA, l15, quad);
        bf16x8 wb  = wfragG(attW1Img, kc, ttB, l15, quad);
        bf16x8 woa = wfragG(outWImg,  kc, ttA, l15, quad);
        bf16x8 wob = wfragG(outWImg,  kc, ttB, l15, quad);
        bf16x8 pf0 = *(const bf16x8*)&sBuf[(32 + l15) * 136 + kc * 32 + fcol];
        bf16x8 pf1 = *(const bf16x8*)&sBuf[(48 + l15) * 136 + kc * 32 + fcol];
        at[0][0] = MFMA16(pf0, wa, at[0][0]);  at[0][1] = MFMA16(pf0, wb, at[0][1]);
        oo[0][0] = MFMA16(pf0, woa, oo[0][0]); oo[0][1] = MFMA16(pf0, wob, oo[0][1]);
        at[1][0] = MFMA16(pf1, wa, at[1][0]);  at[1][1] = MFMA16(pf1, wb, at[1][1]);
        oo[1][0] = MFMA16(pf1, woa, oo[1][0]); oo[1][1] = MFMA16(pf1, wob, oo[1][1]);
    }
    float b1A = att_b1[colA], b1B = att_b1[colB];
    float w2A = att_W2[colA], w2B = att_W2[colB];
    float obA = out_b[colA],  obB = out_b[colB];
#pragma unroll
    for (int rg = 0; rg < 2; rg++)
#pragma unroll
        for (int r = 0; r < 4; r++) {
            float pr = tanhf(at[rg][0][r] + b1A) * w2A + tanhf(at[rg][1][r] + b1B) * w2B;
            outPool[(r0 + rg * 16 + quad * 4 + r) * 128 + colA] = tanhf(oo[rg][0][r] + obA);
            outPool[(r0 + rg * 16 + quad * 4 + r) * 128 + colB] = tanhf(oo[rg][1][r] + obB);
            float v = pr;
            v += __shfl_xor(v, 1); v += __shfl_xor(v, 2);
            v += __shfl_xor(v, 4); v += __shfl_xor(v, 8);
            if (l15 == 0) atomicAdd(&sRed[rg * 16 + quad * 4 + r], v);
        }
    __syncthreads();
    if (t < 32) atten[r0 + t] = sRed[t] + att_b2[0];
}

// ---------------------------------------------------------------- edges out: E0@W3 + ebias
// M=32: each W3 fragment feeds both row-groups (halves weight traffic).
__global__ __launch_bounds__(64) void k_eout(
    const float* __restrict__ E0, const u16* __restrict__ W3Img,
    const float* __restrict__ ebias, float* __restrict__ Eout)
{
    int t = threadIdx.x, l15 = t & 15, quad = t >> 4;
    size_t r0 = (size_t)blockIdx.x * 32;
    bf16x8 eF[2][4];
#pragma unroll
    for (int rg = 0; rg < 2; rg++)
#pragma unroll
        for (int kc = 0; kc < 4; kc++) {
            const float* er = &E0[(r0 + rg * 16 + l15) * 128 + kc * 32 + quad * 8];
            eF[rg][kc] = cvt8(*(const float4*)er, *(const float4*)(er + 4));
        }
    f32x4 acc[2][8];
#pragma unroll
    for (int rg = 0; rg < 2; rg++)
#pragma unroll
        for (int i = 0; i < 8; i++) acc[rg][i] = (f32x4){0.f, 0.f, 0.f, 0.f};
    {
        bf16x8 wc[8], wn[8];
#pragma unroll
        for (int tt = 0; tt < 8; tt++) wc[tt] = wfragG(W3Img, 0, tt, l15, quad);
#pragma unroll
        for (int kc = 0; kc < 4; kc++) {
            if (kc < 3)
#pragma unroll
                for (int tt = 0; tt < 8; tt++) wn[tt] = wfragG(W3Img, kc + 1, tt, l15, quad);
#pragma unroll
            for (int tt = 0; tt < 8; tt++) {
                acc[0][tt] = MFMA16(eF[0][kc], wc[tt], acc[0][tt]);
                acc[1][tt] = MFMA16(eF[1][kc], wc[tt], acc[1][tt]);
            }
            if (kc < 3)
#pragma unroll
                for (int tt = 0; tt < 8; tt++) wc[tt] = wn[tt];
        }
    }
#pragma unroll
    for (int tt = 0; tt < 8; tt++) {
        int col = tt * 16 + l15; float eb = ebias[col];
#pragma unroll
        for (int rg = 0; rg < 2; rg++)
#pragma unroll
            for (int r = 0; r < 4; r++)
                Eout[(r0 + rg * 16 + quad * 4 + r) * 128 + col] = acc[rg][tt][r] + eb;
    }
}

// ---------------------------------------------------------------- softmax-pool + residual
__global__ __launch_bounds__(1024) void k_fin(
    const float* __restrict__ atten, const float* __restrict__ outPool,
    const float* __restrict__ resid,
    float* __restrict__ outRes, float* __restrict__ outMul)
{
    __shared__ float swv[512];
    __shared__ float sred[512];
    __shared__ float sacc[8][128];
    int t = threadIdx.x, b = blockIdx.x;
    float a = 0.f;
    if (t < 512) { a = atten[b * 512 + t]; sred[t] = a; }
    __syncthreads();
    for (int s = 256; s > 0; s >>= 1) { if (t < s) sred[t] = fmaxf(sred[t], sred[t + s]); __syncthreads(); }
    float mx = sred[0]; __syncthreads();
    if (t < 512) { float e = __expf(a - mx); swv[t] = e; sred[t] = e; }
    __syncthreads();
    for (int s = 256; s > 0; s >>= 1) { if (t < s) sred[t] += sred[t + s]; __syncthreads(); }
    float Z = sred[0]; __syncthreads();
    int col = t & 127, q = t >> 7;                     // 8 row-groups of 64
    const float* op = outPool + ((size_t)b * 512 + q * 64) * 128 + col;
    float accM = 0.f;
#pragma unroll 8
    for (int n = 0; n < 64; n++) accM += swv[q * 64 + n] * op[(size_t)n * 128];
    sacc[q][col] = accM;
    __syncthreads();
    if (t < 128) {
        float mulv = (sacc[0][t] + sacc[1][t] + sacc[2][t] + sacc[3][t] +
                      sacc[4][t] + sacc[5][t] + sacc[6][t] + sacc[7][t]) / Z;
        float rv = resid[b * 128 + t] * (1.f / 2560.f);
        outMul[b * 128 + t] = mulv;
        outRes[b * 128 + t] = fmaxf(0.f, tanhf(mulv) + rv);
    }
}

// ================================================================ launch
extern "C" void kernel_launch(void* const* d_in, const int* in_sizes, int n_in,
                              void* d_out, int out_size, void* d_ws, size_t ws_size,
                              hipStream_t stream)
{
    const float* prop0  = (const float*)d_in[0];
    const float* edge0  = (const float*)d_in[1];
    const float* Amat   = (const float*)d_in[2];
    const float* linkW  = (const float*)d_in[4];
    const float* linkb  = (const float*)d_in[5];
    const float* resetW = (const float*)d_in[6];
    const float* resetb = (const float*)d_in[7];
    const float* updateW= (const float*)d_in[8];
    const float* updateb= (const float*)d_in[9];
    const float* transW = (const float*)d_in[10];
    const float* transb = (const float*)d_in[11];
    const float* attW1  = (const float*)d_in[12];
    const float* attb1  = (const float*)d_in[13];
    const float* attW2  = (const float*)d_in[14];
    const float* attb2  = (const float*)d_in[15];
    const float* outW   = (const float*)d_in[16];
    const float* outb   = (const float*)d_in[17];

    char* w = (char*)d_ws;
    float* ws_atten   = (float*)(w + 4259840);        //    65,536 B
    float* ws_resid   = (float*)(w + 4325376);        //    16,384 B
    float* ws_W2      = (float*)(w + 4341760);        //    65,536 B
    float* ws_ebias   = (float*)(w + 4407296);        //       512 B
    u16*   ws_linkImg = (u16*)(w + 4407808);          //    32,768 B
    u16*   ws_W3Img   = (u16*)(w + 4440576);          //    32,768 B
    u16*   ws_WrImg   = (u16*)(w + 4473344);          //    65,536 B
    u16*   ws_WzImg   = (u16*)(w + 4538880);          //    65,536 B
    u16*   ws_WhImg   = (u16*)(w + 4604416);          //    65,536 B
    u16*   ws_attW1Img= (u16*)(w + 4669952);          //    32,768 B
    u16*   ws_outWImg = (u16*)(w + 4702720);          //    32,768 B (~4.7 MB)

    float* out_res  = (float*)d_out;
    float* out_mul  = out_res + 4096;
    float* out_edge = out_res + 8192;
    // Scratch inside d_out edge region (dead until k_eout, which runs last):
    u16*   Eswz     = (u16*)out_edge;                 // 16.78 MB
    float* outPool  = out_edge + 4194304;             // next 8.39 MB

    hipMemsetAsync(ws_resid, 0, 32 * 128 * sizeof(float), stream);
    k_prep1<<<274, 256, 0, stream>>>(linkW, resetW, updateW, transW, attW1, outW,
                                     ws_W2, ws_linkImg, ws_WrImg, ws_WzImg, ws_WhImg,
                                     ws_attW1Img, ws_outWImg);
    k_prep2<<<257, 256, 0, stream>>>(linkW, linkb, ws_W2, ws_W3Img, ws_ebias);
    k_te<<<dim3(64, 32), 256, 0, stream>>>(edge0, Eswz, ws_resid);
    k_main<<<512, 256, 0, stream>>>(Amat, Eswz, prop0,
                                    ws_linkImg, ws_WrImg, ws_WzImg, ws_WhImg,
                                    ws_attW1Img, ws_outWImg,
                                    linkb, resetb, updateb, transb,
                                    attb1, attW2, attb2, outb,
                                    ws_atten, outPool, ws_resid);
    k_fin<<<32, 1024, 0, stream>>>(ws_atten, outPool, ws_resid, out_res, out_mul);
    k_eout<<<2048, 64, 0, stream>>>(edge0, ws_W3Img, ws_ebias, out_edge);
}